// Round 9
// baseline (4332.231 us; speedup 1.0000x reference)
//
#include <hip/hip_runtime.h>
#include <hip/hip_bf16.h>
#include <math.h>

#define N_NODES 50000
#define N_EDGES 200000
#define N_GRAPH 1024
#define HC      128
#define NFC     256
#define NLAYER  5
#define NFFC    512

enum { EPI_NONE=0, EPI_SSP=2, EPI_RELU_RES=3 };

typedef short bf16x8 __attribute__((ext_vector_type(8)));
typedef float f4v    __attribute__((ext_vector_type(4)));

__device__ __forceinline__ float ssp_f(float x) {
  return fmaxf(x, 0.0f) + log1pf(expf(-fabsf(x))) - 0.69314718055994530942f;
}
__device__ __forceinline__ unsigned short f2bf(float x) {
  union { float f; unsigned u; } v; v.f = x;
  unsigned r = v.u + 0x7fff + ((v.u >> 16) & 1);
  return (unsigned short)(r >> 16);
}
__device__ __forceinline__ float bf2f(unsigned short b) {
  union { unsigned u; float f; } v; v.u = (unsigned)b << 16; return v.f;
}

// ---------------------------------------------------------------------------
__global__ void zero_kernel(float4* __restrict__ p, int n4) {
  int i = blockIdx.x * blockDim.x + threadIdx.x;
  if (i < n4) p[i] = make_float4(0.f, 0.f, 0.f, 0.f);
}
__global__ void zeroi_kernel(int* __restrict__ p, int n) {
  int i = blockIdx.x * blockDim.x + threadIdx.x;
  if (i < n) p[i] = 0;
}

// ---- dst-sort infrastructure (ei fixed input; rebuilt every call) ----------
__global__ void hist_kernel(const int* __restrict__ ei, int* __restrict__ deg) {
  int e = blockIdx.x * blockDim.x + threadIdx.x;
  if (e < N_EDGES) atomicAdd(&deg[ei[N_EDGES + e]], 1);
}
__global__ __launch_bounds__(1024) void scan_kernel(
    const int* __restrict__ deg, int* __restrict__ cursor, int n) {
  __shared__ int buf[1024];
  __shared__ int carry;
  if (threadIdx.x == 0) carry = 0;
  __syncthreads();
  for (int base = 0; base < n; base += 1024) {
    int i = base + threadIdx.x;
    int v = (i < n) ? deg[i] : 0;
    buf[threadIdx.x] = v;
    __syncthreads();
    for (int s = 1; s < 1024; s <<= 1) {
      int t = (threadIdx.x >= s) ? buf[threadIdx.x - s] : 0;
      __syncthreads();
      buf[threadIdx.x] += t;
      __syncthreads();
    }
    int excl = carry + buf[threadIdx.x] - v;
    if (i < n) cursor[i] = excl;
    int tot = buf[1023];
    __syncthreads();
    if (threadIdx.x == 0) carry += tot;
    __syncthreads();
  }
}
__global__ void perm_kernel(const int* __restrict__ ei, int* __restrict__ cursor,
                            int* __restrict__ perm) {
  int e = blockIdx.x * blockDim.x + threadIdx.x;
  if (e < N_EDGES) {
    int d = ei[N_EDGES + e];
    int p = atomicAdd(&cursor[d], 1);
    perm[p] = e;
  }
}

// split fp32 weights -> bf16 hi + lo
__global__ void wsplit_kernel(const float* __restrict__ w,
                              unsigned short* __restrict__ hi,
                              unsigned short* __restrict__ lo, int n) {
  int i = blockIdx.x * blockDim.x + threadIdx.x;
  if (i < n) {
    float v = w[i];
    unsigned short hb = f2bf(v);
    hi[i] = hb;
    lo[i] = f2bf(v - bf2f(hb));
  }
}

__global__ void embed_kernel(const int* __restrict__ x, const float* __restrict__ pos,
                             const float* __restrict__ vert, const float* __restrict__ posw,
                             float* __restrict__ h) {
  int n = blockIdx.x;
  int c = threadIdx.x;            // 128 threads
  float v;
  if (c < 80) {
    v = vert[(size_t)x[n] * 80 + c];
  } else {
    int j = c - 80;
    v = pos[n*3+0]*posw[j*3+0] + pos[n*3+1]*posw[j*3+1] + pos[n*3+2]*posw[j*3+2];
  }
  h[(size_t)n*HC + c] = v;
}

// ea (split bf16 hi/lo) = edge_attr @ edge_w.T
__global__ void edgeproj_kernel(const float* __restrict__ eattr, const float* __restrict__ ew,
                                unsigned short* __restrict__ eah,
                                unsigned short* __restrict__ eal) {
  int idx = blockIdx.x * blockDim.x + threadIdx.x;
  if (idx >= N_EDGES * HC) return;
  int e = idx >> 7, c = idx & 127;
  const float* a = eattr + (size_t)e*4;
  const float* w = ew + (size_t)c*4;
  float v = a[0]*w[0] + a[1]*w[1] + a[2]*w[2] + a[3]*w[3];
  unsigned short hb = f2bf(v);
  eah[idx] = hb;
  eal[idx] = f2bf(v - bf2f(hb));
}

// ---------------------------------------------------------------------------
// Split-bf16 MFMA GEMM: C[M,N] = epi(A @ B^T + bias) (+resid).
// B pre-split bf16 hi/lo in global; fragments read directly (L2-hot weights).
// Tile 128x128, BK=32, 256 threads.
template<int EPI>
__global__ __launch_bounds__(256, 2) void mgemm(
    const float* A0,
    const unsigned short* __restrict__ Bh, const unsigned short* __restrict__ Bl,
    const float* __restrict__ bias, const float* resid, float* C,
    int M, int K, int N)
{
  __shared__ unsigned short lds[2 * 128 * 40];   // A hi/lo, pitch 40
  const int AH = 0, AL = 5120;

  const int tid  = threadIdx.x;
  const int m0   = blockIdx.x * 128;
  const int n0   = blockIdx.y * 128;
  const int lane = tid & 63, wave = tid >> 6;
  const int quad = lane >> 4, l16 = lane & 15;
  const int wm = (wave >> 1) * 64, wn = (wave & 1) * 64;
  const int r  = tid >> 1;
  const int c0 = (tid & 1) * 16;

  f4v acc[4][4];
  const f4v zf = {0.f, 0.f, 0.f, 0.f};
#pragma unroll
  for (int i = 0; i < 4; i++)
#pragma unroll
    for (int j = 0; j < 4; j++) acc[i][j] = zf;

  const bool mok = (m0 + r) < M;
  const size_t arow = (size_t)(m0 + r);

  for (int kk = 0; kk < K; kk += 32) {
    float av[16];
    const int kg = kk + c0;
    if (mok) {
      const float* ap = A0 + arow * K + kg;
#pragma unroll
      for (int q = 0; q < 4; q++) *(float4*)&av[q*4] = *(const float4*)(ap + q*4);
    } else {
#pragma unroll
      for (int j = 0; j < 16; j++) av[j] = 0.f;
    }

    bf16x8 bh[4], bl[4];
#pragma unroll
    for (int nt = 0; nt < 4; nt++) {
      const size_t brow = (size_t)(n0 + wn + nt*16 + l16);
      bh[nt] = *(const bf16x8*)&Bh[brow * K + kk + quad*8];
      bl[nt] = *(const bf16x8*)&Bl[brow * K + kk + quad*8];
    }

    __syncthreads();

    unsigned short th[16], tl[16];
#pragma unroll
    for (int j = 0; j < 16; j++) {
      unsigned short hb = f2bf(av[j]);
      th[j] = hb; tl[j] = f2bf(av[j] - bf2f(hb));
    }
    *(bf16x8*)&lds[AH + r*40 + c0]     = *(bf16x8*)&th[0];
    *(bf16x8*)&lds[AH + r*40 + c0 + 8] = *(bf16x8*)&th[8];
    *(bf16x8*)&lds[AL + r*40 + c0]     = *(bf16x8*)&tl[0];
    *(bf16x8*)&lds[AL + r*40 + c0 + 8] = *(bf16x8*)&tl[8];

    __syncthreads();

    bf16x8 ah[4], al[4];
#pragma unroll
    for (int t = 0; t < 4; t++) {
      const int ra = (wm + t*16 + l16) * 40 + quad * 8;
      ah[t] = *(const bf16x8*)&lds[AH + ra];
      al[t] = *(const bf16x8*)&lds[AL + ra];
    }
#pragma unroll
    for (int mt = 0; mt < 4; mt++)
#pragma unroll
      for (int nt = 0; nt < 4; nt++) {
        acc[mt][nt] = __builtin_amdgcn_mfma_f32_16x16x32_bf16(ah[mt], bh[nt], acc[mt][nt], 0, 0, 0);
        acc[mt][nt] = __builtin_amdgcn_mfma_f32_16x16x32_bf16(ah[mt], bl[nt], acc[mt][nt], 0, 0, 0);
        acc[mt][nt] = __builtin_amdgcn_mfma_f32_16x16x32_bf16(al[mt], bh[nt], acc[mt][nt], 0, 0, 0);
      }
  }

#pragma unroll
  for (int nt = 0; nt < 4; nt++) {
    const int ncol = n0 + wn + nt*16 + l16;
    float bz = 0.f;
    if constexpr (EPI != EPI_NONE) bz = bias[ncol];
#pragma unroll
    for (int mt = 0; mt < 4; mt++) {
      const int mb = wm + mt*16 + quad*4;
#pragma unroll
      for (int rr = 0; rr < 4; rr++) {
        const int m = m0 + mb + rr;
        if (m >= M) continue;
        float v = acc[mt][nt][rr] + bz;
        if constexpr (EPI == EPI_SSP)           v = ssp_f(v);
        else if constexpr (EPI == EPI_RELU_RES) v = fmaxf(v, 0.f);
        if constexpr (EPI == EPI_RELU_RES)
          v += resid[(size_t)m * N + ncol];
        C[(size_t)m * N + ncol] = v;
      }
    }
  }
}

// ---------------------------------------------------------------------------
// Edge-MLP GEMM: ea = tanh(cat(ea, h[src]+h[dst]) @ emw^T + emb) + ea,
// with ea stored SPLIT (eah/eal bf16). Lower-K A-operand + residual read from
// split form (no conversion); output written back split. In-place safe: each
// block reads/writes only its own 128 rows; all ea reads precede epilogue.
__global__ __launch_bounds__(256, 2) void emgemm(
    unsigned short* eah, unsigned short* eal,
    const unsigned short* __restrict__ Bh, const unsigned short* __restrict__ Bl,
    const float* __restrict__ bias, const int* __restrict__ ei,
    const float* __restrict__ hgat)
{
  __shared__ unsigned short lds[2 * 128 * 40];
  __shared__ int sS[128], sD[128];
  const int AH = 0, AL = 5120;
  const int M = N_EDGES, K = 2*HC;

  const int tid  = threadIdx.x;
  const int m0   = blockIdx.x * 128;
  const int lane = tid & 63, wave = tid >> 6;
  const int quad = lane >> 4, l16 = lane & 15;
  const int wm = (wave >> 1) * 64, wn = (wave & 1) * 64;
  const int r  = tid >> 1;
  const int c0 = (tid & 1) * 16;

  if (tid < 128) {
    int e  = m0 + tid;
    int ge = (e < M) ? e : (M - 1);
    sS[tid] = ei[ge];
    sD[tid] = ei[N_EDGES + ge];
  }

  f4v acc[4][4];
  const f4v zf = {0.f, 0.f, 0.f, 0.f};
#pragma unroll
  for (int i = 0; i < 4; i++)
#pragma unroll
    for (int j = 0; j < 4; j++) acc[i][j] = zf;

  const bool mok = (m0 + r) < M;
  const size_t arow = (size_t)(m0 + r);

  __syncthreads();

  for (int kk = 0; kk < K; kk += 32) {
    const int kg = kk + c0;
    unsigned short th[16], tl[16];
    if (kg < HC) {
      // pure bf16 copy from split ea (no conversion)
      if (mok) {
        const size_t base = arow * HC + kg;
        *(bf16x8*)&th[0] = *(const bf16x8*)&eah[base];
        *(bf16x8*)&th[8] = *(const bf16x8*)&eah[base + 8];
        *(bf16x8*)&tl[0] = *(const bf16x8*)&eal[base];
        *(bf16x8*)&tl[8] = *(const bf16x8*)&eal[base + 8];
      } else {
#pragma unroll
        for (int j = 0; j < 16; j++) { th[j] = 0; tl[j] = 0; }
      }
    } else {
      float av[16];
      if (mok) {
        const float* p1 = hgat + (size_t)sS[r] * HC + (kg - HC);
        const float* p2 = hgat + (size_t)sD[r] * HC + (kg - HC);
#pragma unroll
        for (int q = 0; q < 4; q++) {
          float4 xa = *(const float4*)(p1 + q*4);
          float4 xb = *(const float4*)(p2 + q*4);
          av[q*4+0] = xa.x + xb.x; av[q*4+1] = xa.y + xb.y;
          av[q*4+2] = xa.z + xb.z; av[q*4+3] = xa.w + xb.w;
        }
      } else {
#pragma unroll
        for (int j = 0; j < 16; j++) av[j] = 0.f;
      }
#pragma unroll
      for (int j = 0; j < 16; j++) {
        unsigned short hb = f2bf(av[j]);
        th[j] = hb; tl[j] = f2bf(av[j] - bf2f(hb));
      }
    }

    bf16x8 bh[4], bl[4];
#pragma unroll
    for (int nt = 0; nt < 4; nt++) {
      const size_t brow = (size_t)(wn + nt*16 + l16);
      bh[nt] = *(const bf16x8*)&Bh[brow * K + kk + quad*8];
      bl[nt] = *(const bf16x8*)&Bl[brow * K + kk + quad*8];
    }

    __syncthreads();

    *(bf16x8*)&lds[AH + r*40 + c0]     = *(bf16x8*)&th[0];
    *(bf16x8*)&lds[AH + r*40 + c0 + 8] = *(bf16x8*)&th[8];
    *(bf16x8*)&lds[AL + r*40 + c0]     = *(bf16x8*)&tl[0];
    *(bf16x8*)&lds[AL + r*40 + c0 + 8] = *(bf16x8*)&tl[8];

    __syncthreads();

    bf16x8 ah[4], al[4];
#pragma unroll
    for (int t = 0; t < 4; t++) {
      const int ra = (wm + t*16 + l16) * 40 + quad * 8;
      ah[t] = *(const bf16x8*)&lds[AH + ra];
      al[t] = *(const bf16x8*)&lds[AL + ra];
    }
#pragma unroll
    for (int mt = 0; mt < 4; mt++)
#pragma unroll
      for (int nt = 0; nt < 4; nt++) {
        acc[mt][nt] = __builtin_amdgcn_mfma_f32_16x16x32_bf16(ah[mt], bh[nt], acc[mt][nt], 0, 0, 0);
        acc[mt][nt] = __builtin_amdgcn_mfma_f32_16x16x32_bf16(ah[mt], bl[nt], acc[mt][nt], 0, 0, 0);
        acc[mt][nt] = __builtin_amdgcn_mfma_f32_16x16x32_bf16(al[mt], bh[nt], acc[mt][nt], 0, 0, 0);
      }
  }

#pragma unroll
  for (int nt = 0; nt < 4; nt++) {
    const int ncol = wn + nt*16 + l16;
    const float bz = bias[ncol];
#pragma unroll
    for (int mt = 0; mt < 4; mt++) {
      const int mb = wm + mt*16 + quad*4;
#pragma unroll
      for (int rr = 0; rr < 4; rr++) {
        const int m = m0 + mb + rr;
        if (m >= M) continue;
        const size_t idx = (size_t)m * HC + ncol;
        float v = tanhf(acc[mt][nt][rr] + bz);
        v += bf2f(eah[idx]) + bf2f(eal[idx]);   // residual from split
        unsigned short hb = f2bf(v);
        eah[idx] = hb;
        eal[idx] = f2bf(v - bf2f(hb));
      }
    }
  }
}

// ---------------------------------------------------------------------------
// Fused filter MLP + in-register run-reduced scatter over DST-SORTED edges.
// 64-edge tile, 256 threads, LDS 53760 B -> 3 blocks/CU.
// ea comes PRE-SPLIT (eah/eal) -> staging is pure copies, no VALU conversion.
// XCD swizzle: grid padded to 3128 = 8*391; sb=(bid&7)*391+(bid>>3) keeps
// contiguous dst-sorted chunks (~6.4 MB agg) on one XCD's L2.
__device__ __forceinline__ int sigma_row(int r) {
  return ((r >> 2) & 3) * 16 + (r >> 4) * 4 + (r & 3);
}
__global__ __launch_bounds__(256, 3) void ffs_kernel(
    const unsigned short* __restrict__ eah, const unsigned short* __restrict__ eal,
    const unsigned short* __restrict__ fw1h, const unsigned short* __restrict__ fw1l,
    const float* __restrict__ fb1,
    const unsigned short* __restrict__ fw2h, const unsigned short* __restrict__ fw2l,
    const float* __restrict__ fb2, const int* __restrict__ ei,
    const int* __restrict__ perm,
    const float* __restrict__ h1, float* agg)
{
  __shared__ unsigned short ldsA[2][64][136];   // ea hi/lo        34816 B
  __shared__ unsigned short ldsT[2][64][72];    // T phase chunk   18432 B
  __shared__ int sS[64], sD[64];                //                   512 B

  const int sb = ((int)blockIdx.x & 7) * 391 + ((int)blockIdx.x >> 3);
  const int m0 = sb * 64;
  if (m0 >= N_EDGES) return;                    // 3 pad blocks exit whole

  const int tid  = threadIdx.x;
  const int lane = tid & 63, wave = tid >> 6;     // wave 0..3
  const int quad = lane >> 4, l16 = lane & 15;

  // stage ea tile 64x128 (row-permuted, pre-split -> pure copies)
  {
    const int r = tid >> 2, cb = (tid & 3) * 32;
    const int pe = perm[m0 + sigma_row(r)];
    const size_t base = (size_t)pe * HC + cb;
#pragma unroll
    for (int q = 0; q < 4; q++) {
      *(bf16x8*)&ldsA[0][r][cb + q*8] = *(const bf16x8*)&eah[base + q*8];
      *(bf16x8*)&ldsA[1][r][cb + q*8] = *(const bf16x8*)&eal[base + q*8];
    }
  }
  if (tid < 64) {
    int pe = perm[m0 + sigma_row(tid)];
    sS[tid] = ei[pe];
    sD[tid] = ei[N_EDGES + pe];
  }

  f4v wacc[4][4];
  const f4v zf = {0.f, 0.f, 0.f, 0.f};
#pragma unroll
  for (int mt = 0; mt < 4; mt++)
#pragma unroll
    for (int nt = 0; nt < 4; nt++) wacc[mt][nt] = zf;

  __syncthreads();

  // ---- prefetch h1 gather values for the epilogue (overlaps all compute) ----
  float hp[4][4][4];   // [mt][rr][nt]
#pragma unroll
  for (int mt = 0; mt < 4; mt++)
#pragma unroll
    for (int rr = 0; rr < 4; rr++) {
      const int src = sS[mt*16 + quad*4 + rr];
      const float* hr = h1 + (size_t)src * NFC + wave*64 + l16;
#pragma unroll
      for (int nt = 0; nt < 4; nt++) hp[mt][rr][nt] = hr[nt*16];
    }

  for (int p = 0; p < 4; p++) {
    // ---- GEMM1: T_p[64,64]; wave owns COLS (fw1 fragments wave-distinct) ----
    f4v tacc[4];
#pragma unroll
    for (int mt = 0; mt < 4; mt++) tacc[mt] = zf;
    const size_t b1row = (size_t)(p*64 + wave*16 + l16);
#pragma unroll
    for (int kk = 0; kk < 128; kk += 32) {
      bf16x8 bh = *(const bf16x8*)&fw1h[b1row * HC + kk + quad*8];
      bf16x8 bl = *(const bf16x8*)&fw1l[b1row * HC + kk + quad*8];
#pragma unroll
      for (int mt = 0; mt < 4; mt++) {
        bf16x8 ah = *(const bf16x8*)&ldsA[0][mt*16 + l16][kk + quad*8];
        bf16x8 al = *(const bf16x8*)&ldsA[1][mt*16 + l16][kk + quad*8];
        tacc[mt] = __builtin_amdgcn_mfma_f32_16x16x32_bf16(ah, bh, tacc[mt], 0, 0, 0);
        tacc[mt] = __builtin_amdgcn_mfma_f32_16x16x32_bf16(ah, bl, tacc[mt], 0, 0, 0);
        tacc[mt] = __builtin_amdgcn_mfma_f32_16x16x32_bf16(al, bh, tacc[mt], 0, 0, 0);
      }
    }
    // ssp + split -> T LDS (C layout: col = wave*16+l16, row = mt*16+quad*4+rr)
    {
      const int col = wave*16 + l16;
      const float bz = fb1[p*64 + col];
#pragma unroll
      for (int mt = 0; mt < 4; mt++) {
        const int rowb = mt*16 + quad*4;
#pragma unroll
        for (int rr = 0; rr < 4; rr++) {
          float v = ssp_f(tacc[mt][rr] + bz);
          unsigned short hb = f2bf(v);
          ldsT[0][rowb+rr][col] = hb;
          ldsT[1][rowb+rr][col] = f2bf(v - bf2f(hb));
        }
      }
    }
    __syncthreads();

    // ---- GEMM2 partial: W += T_p @ fw2[:, p*64..+64]^T (B wave-distinct) ----
#pragma unroll
    for (int kc = 0; kc < 2; kc++) {
      bf16x8 a_h[4], a_l[4];
#pragma unroll
      for (int mt = 0; mt < 4; mt++) {
        a_h[mt] = *(const bf16x8*)&ldsT[0][mt*16 + l16][kc*32 + quad*8];
        a_l[mt] = *(const bf16x8*)&ldsT[1][mt*16 + l16][kc*32 + quad*8];
      }
#pragma unroll
      for (int nt = 0; nt < 4; nt++) {
        const size_t brow = (size_t)(wave*64 + nt*16 + l16);
        bf16x8 bh = *(const bf16x8*)&fw2h[brow * NFC + p*64 + kc*32 + quad*8];
        bf16x8 bl = *(const bf16x8*)&fw2l[brow * NFC + p*64 + kc*32 + quad*8];
#pragma unroll
        for (int mt = 0; mt < 4; mt++) {
          wacc[mt][nt] = __builtin_amdgcn_mfma_f32_16x16x32_bf16(a_h[mt], bh, wacc[mt][nt], 0, 0, 0);
          wacc[mt][nt] = __builtin_amdgcn_mfma_f32_16x16x32_bf16(a_h[mt], bl, wacc[mt][nt], 0, 0, 0);
          wacc[mt][nt] = __builtin_amdgcn_mfma_f32_16x16x32_bf16(a_l[mt], bh, wacc[mt][nt], 0, 0, 0);
        }
      }
    }
    __syncthreads();   // T reads done before next phase overwrites
  }

  // ---- in-register run-reduced scatter (uses prefetched hp) ----
#pragma unroll
  for (int nt = 0; nt < 4; nt++) {
    const int col = wave*64 + nt*16 + l16;
    const float bz = fb2[col];
    float accum = 0.f;
    int prev = -1;
#pragma unroll
    for (int mt = 0; mt < 4; mt++) {
#pragma unroll
      for (int rr = 0; rr < 4; rr++) {
        const int prow = mt*16 + quad*4 + rr;
        const int d = sD[prow];
        const float v = (wacc[mt][nt][rr] + bz) * hp[mt][rr][nt];
        if (d != prev) {
          if (prev >= 0) atomicAdd(&agg[(size_t)prev * NFC + col], accum);
          accum = v; prev = d;
        } else {
          accum += v;
        }
      }
    }
    atomicAdd(&agg[(size_t)prev * NFC + col], accum);
  }
}

// ---------------------------------------------------------------------------
__global__ void pool_kernel(const int* __restrict__ batch, const float* __restrict__ h,
                            float* __restrict__ ssum, float* __restrict__ cnt) {
  int idx = blockIdx.x * blockDim.x + threadIdx.x;
  if (idx >= N_NODES * HC) return;
  int n = idx >> 7, c = idx & 127;
  int b = batch[n];
  atomicAdd(&ssum[(size_t)b*HC + c], h[idx]);
  if (c == 0) atomicAdd(&cnt[b], 1.0f);
}

__global__ __launch_bounds__(256) void head_kernel(
    const float* __restrict__ ssum, const float* __restrict__ cnt,
    const float* __restrict__ w1, const float* __restrict__ b1,
    const float* __restrict__ w2, const float* __restrict__ b2,
    float* __restrict__ y) {
  int g = blockIdx.x;
  __shared__ float gs[HC];
  __shared__ float red[256];
  int tid = threadIdx.x;
  float inv = 1.0f / fmaxf(cnt[g], 1.0f);
  if (tid < HC) gs[tid] = ssum[(size_t)g*HC + tid] * inv;
  __syncthreads();
  float partial = 0.0f;
  for (int f = tid; f < NFFC; f += 256) {
    float acc = b1[f];
    const float* wr = w1 + (size_t)f*HC;
#pragma unroll 8
    for (int k = 0; k < HC; k++) acc = fmaf(gs[k], wr[k], acc);
    float t = 0.5f * acc * (1.0f + erff(acc * 0.70710678118654752440f));
    partial = fmaf(t, w2[f], partial);
  }
  red[tid] = partial;
  __syncthreads();
  for (int s = 128; s > 0; s >>= 1) {
    if (tid < s) red[tid] += red[tid + s];
    __syncthreads();
  }
  if (tid == 0) y[g] = red[0] + b2[0];
}

// ---------------------------------------------------------------------------
extern "C" void kernel_launch(void* const* d_in, const int* in_sizes, int n_in,
                              void* d_out, int out_size, void* d_ws, size_t ws_size,
                              hipStream_t stream) {
  const int*   x     = (const int*)  d_in[0];
  const int*   ei    = (const int*)  d_in[1];
  const float* eattr = (const float*)d_in[2];
  const int*   batch = (const int*)  d_in[3];
  const float* pos   = (const float*)d_in[4];
  const float* vert  = (const float*)d_in[5];
  const float* posw  = (const float*)d_in[6];
  const float* edgew = (const float*)d_in[7];
  const float* fw1   = (const float*)d_in[8];
  const float* fb1   = (const float*)d_in[9];
  const float* fw2   = (const float*)d_in[10];
  const float* fb2   = (const float*)d_in[11];
  const float* l1w   = (const float*)d_in[12];
  const float* l2w   = (const float*)d_in[13];
  const float* l2b   = (const float*)d_in[14];
  const float* l3w   = (const float*)d_in[15];
  const float* l3b   = (const float*)d_in[16];
  const float* emw   = (const float*)d_in[17];
  const float* emb   = (const float*)d_in[18];
  const float* hw1   = (const float*)d_in[19];
  const float* hb1   = (const float*)d_in[20];
  const float* hw2   = (const float*)d_in[21];
  const float* hb2   = (const float*)d_in[22];
  float* out = (float*)d_out;

  char* ws = (char*)d_ws;
  size_t off = 0;
  auto alloc = [&](size_t bytes) { char* p = ws + off; off += (bytes + 511) & ~(size_t)511; return p; };
  unsigned short* eah = (unsigned short*)alloc((size_t)N_EDGES*HC*2);  // split ea
  unsigned short* eal = (unsigned short*)alloc((size_t)N_EDGES*HC*2);
  float* h    = (float*)alloc((size_t)N_NODES*HC*4);
  float* h1   = (float*)alloc((size_t)N_NODES*NFC*4);
  float* agg  = (float*)alloc((size_t)N_NODES*NFC*4);
  float* ssum = (float*)alloc((size_t)N_GRAPH*HC*4);
  float* cnt  = (float*)alloc((size_t)N_GRAPH*4);
  int* deg    = (int*)alloc((size_t)(N_NODES+1)*4);
  int* cursor = (int*)alloc((size_t)(N_NODES+1)*4);
  int* perm   = (int*)alloc((size_t)N_EDGES*4);
  const int n_fw1 = NLAYER*NFC*HC, n_fw2 = NLAYER*NFC*NFC, n_l1 = NLAYER*NFC*HC;
  const int n_l2 = NLAYER*HC*NFC, n_l3 = NLAYER*HC*HC, n_em = NLAYER*HC*2*HC;
  unsigned short* fw1h = (unsigned short*)alloc((size_t)n_fw1*2);
  unsigned short* fw1l = (unsigned short*)alloc((size_t)n_fw1*2);
  unsigned short* fw2h = (unsigned short*)alloc((size_t)n_fw2*2);
  unsigned short* fw2l = (unsigned short*)alloc((size_t)n_fw2*2);
  unsigned short* l1h  = (unsigned short*)alloc((size_t)n_l1*2);
  unsigned short* l1l  = (unsigned short*)alloc((size_t)n_l1*2);
  unsigned short* l2h  = (unsigned short*)alloc((size_t)n_l2*2);
  unsigned short* l2l  = (unsigned short*)alloc((size_t)n_l2*2);
  unsigned short* l3h  = (unsigned short*)alloc((size_t)n_l3*2);
  unsigned short* l3l  = (unsigned short*)alloc((size_t)n_l3*2);
  unsigned short* emh  = (unsigned short*)alloc((size_t)n_em*2);
  unsigned short* eml  = (unsigned short*)alloc((size_t)n_em*2);

  zeroi_kernel<<<(N_NODES+1+255)/256, 256, 0, stream>>>(deg, N_NODES+1);
  hist_kernel<<<(N_EDGES+255)/256, 256, 0, stream>>>(ei, deg);
  scan_kernel<<<1, 1024, 0, stream>>>(deg, cursor, N_NODES+1);
  perm_kernel<<<(N_EDGES+255)/256, 256, 0, stream>>>(ei, cursor, perm);

  wsplit_kernel<<<(n_fw1+255)/256, 256, 0, stream>>>(fw1, fw1h, fw1l, n_fw1);
  wsplit_kernel<<<(n_fw2+255)/256, 256, 0, stream>>>(fw2, fw2h, fw2l, n_fw2);
  wsplit_kernel<<<(n_l1 +255)/256, 256, 0, stream>>>(l1w, l1h, l1l, n_l1);
  wsplit_kernel<<<(n_l2 +255)/256, 256, 0, stream>>>(l2w, l2h, l2l, n_l2);
  wsplit_kernel<<<(n_l3 +255)/256, 256, 0, stream>>>(l3w, l3h, l3l, n_l3);
  wsplit_kernel<<<(n_em +255)/256, 256, 0, stream>>>(emw, emh, eml, n_em);

  const int GN    = (N_NODES + 127) / 128;   // 391
  const int GE    = (N_EDGES + 127) / 128;   // 1563
  const int GE64S = 3128;                    // 8 * 391, XCD-swizzled

  embed_kernel<<<N_NODES, 128, 0, stream>>>(x, pos, vert, posw, h);
  edgeproj_kernel<<<(N_EDGES*HC + 255)/256, 256, 0, stream>>>(eattr, edgew, eah, eal);

  for (int i = 0; i < NLAYER; ++i) {
    mgemm<EPI_NONE><<<dim3(GN,2), 256, 0, stream>>>(
        h, l1h + (size_t)i*NFC*HC, l1l + (size_t)i*NFC*HC, nullptr, nullptr, h1,
        N_NODES, HC, NFC);
    zero_kernel<<<((N_NODES*NFC/4) + 255)/256, 256, 0, stream>>>(
        (float4*)agg, N_NODES*NFC/4);
    ffs_kernel<<<GE64S, 256, 0, stream>>>(
        eah, eal, fw1h + (size_t)i*NFC*HC, fw1l + (size_t)i*NFC*HC, fb1 + (size_t)i*NFC,
        fw2h + (size_t)i*NFC*NFC, fw2l + (size_t)i*NFC*NFC, fb2 + (size_t)i*NFC,
        ei, perm, h1, agg);
    mgemm<EPI_SSP><<<dim3(GN,1), 256, 0, stream>>>(
        agg, l2h + (size_t)i*HC*NFC, l2l + (size_t)i*HC*NFC, l2b + (size_t)i*HC,
        nullptr, h1, N_NODES, NFC, HC);
    mgemm<EPI_RELU_RES><<<dim3(GN,1), 256, 0, stream>>>(
        h1, l3h + (size_t)i*HC*HC, l3l + (size_t)i*HC*HC, l3b + (size_t)i*HC,
        h, h, N_NODES, HC, HC);
    emgemm<<<GE, 256, 0, stream>>>(
        eah, eal, emh + (size_t)i*HC*2*HC, eml + (size_t)i*HC*2*HC, emb + (size_t)i*HC,
        ei, h);
  }

  zero_kernel<<<((N_GRAPH*HC/4) + 255)/256, 256, 0, stream>>>((float4*)ssum, N_GRAPH*HC/4);
  zero_kernel<<<((N_GRAPH/4) + 255)/256, 256, 0, stream>>>((float4*)cnt, N_GRAPH/4);
  pool_kernel<<<(N_NODES*HC + 255)/256, 256, 0, stream>>>(batch, h, ssum, cnt);
  head_kernel<<<N_GRAPH, 256, 0, stream>>>(ssum, cnt, hw1, hb1, hw2, hb2, out);
}

// Round 10
// 3321.441 us; speedup vs baseline: 1.3043x; 1.3043x over previous
//
#include <hip/hip_runtime.h>
#include <hip/hip_bf16.h>
#include <math.h>

#define N_NODES 50000
#define N_EDGES 200000
#define N_GRAPH 1024
#define HC      128
#define NFC     256
#define NLAYER  5
#define NFFC    512

enum { EPI_NONE=0, EPI_SSP=2, EPI_RELU_RES=3, EPI_TANH_RES=4 };

typedef short bf16x8 __attribute__((ext_vector_type(8)));
typedef float f4v    __attribute__((ext_vector_type(4)));

__device__ __forceinline__ float ssp_f(float x) {
  return fmaxf(x, 0.0f) + log1pf(expf(-fabsf(x))) - 0.69314718055994530942f;
}
__device__ __forceinline__ unsigned short f2bf(float x) {
  union { float f; unsigned u; } v; v.f = x;
  unsigned r = v.u + 0x7fff + ((v.u >> 16) & 1);
  return (unsigned short)(r >> 16);
}
__device__ __forceinline__ float bf2f(unsigned short b) {
  union { unsigned u; float f; } v; v.u = (unsigned)b << 16; return v.f;
}

// ---------------------------------------------------------------------------
__global__ void zero_kernel(float4* __restrict__ p, int n4) {
  int i = blockIdx.x * blockDim.x + threadIdx.x;
  if (i < n4) p[i] = make_float4(0.f, 0.f, 0.f, 0.f);
}
__global__ void zeroi_kernel(int* __restrict__ p, int n) {
  int i = blockIdx.x * blockDim.x + threadIdx.x;
  if (i < n) p[i] = 0;
}

// ---- dst-sort infrastructure (ei fixed input; rebuilt every call) ----------
__global__ void hist_kernel(const int* __restrict__ ei, int* __restrict__ deg) {
  int e = blockIdx.x * blockDim.x + threadIdx.x;
  if (e < N_EDGES) atomicAdd(&deg[ei[N_EDGES + e]], 1);
}
__global__ __launch_bounds__(1024) void scan_kernel(
    const int* __restrict__ deg, int* __restrict__ cursor, int n) {
  __shared__ int buf[1024];
  __shared__ int carry;
  if (threadIdx.x == 0) carry = 0;
  __syncthreads();
  for (int base = 0; base < n; base += 1024) {
    int i = base + threadIdx.x;
    int v = (i < n) ? deg[i] : 0;
    buf[threadIdx.x] = v;
    __syncthreads();
    for (int s = 1; s < 1024; s <<= 1) {
      int t = (threadIdx.x >= s) ? buf[threadIdx.x - s] : 0;
      __syncthreads();
      buf[threadIdx.x] += t;
      __syncthreads();
    }
    int excl = carry + buf[threadIdx.x] - v;
    if (i < n) cursor[i] = excl;
    int tot = buf[1023];
    __syncthreads();
    if (threadIdx.x == 0) carry += tot;
    __syncthreads();
  }
}
__global__ void perm_kernel(const int* __restrict__ ei, int* __restrict__ cursor,
                            int* __restrict__ perm) {
  int e = blockIdx.x * blockDim.x + threadIdx.x;
  if (e < N_EDGES) {
    int d = ei[N_EDGES + e];
    int p = atomicAdd(&cursor[d], 1);
    perm[p] = e;
  }
}

// split fp32 weights -> bf16 hi + lo
__global__ void wsplit_kernel(const float* __restrict__ w,
                              unsigned short* __restrict__ hi,
                              unsigned short* __restrict__ lo, int n) {
  int i = blockIdx.x * blockDim.x + threadIdx.x;
  if (i < n) {
    float v = w[i];
    unsigned short hb = f2bf(v);
    hi[i] = hb;
    lo[i] = f2bf(v - bf2f(hb));
  }
}

__global__ void embed_kernel(const int* __restrict__ x, const float* __restrict__ pos,
                             const float* __restrict__ vert, const float* __restrict__ posw,
                             float* __restrict__ h) {
  int n = blockIdx.x;
  int c = threadIdx.x;            // 128 threads
  float v;
  if (c < 80) {
    v = vert[(size_t)x[n] * 80 + c];
  } else {
    int j = c - 80;
    v = pos[n*3+0]*posw[j*3+0] + pos[n*3+1]*posw[j*3+1] + pos[n*3+2]*posw[j*3+2];
  }
  h[(size_t)n*HC + c] = v;
}

__global__ void edgeproj_kernel(const float* __restrict__ eattr, const float* __restrict__ ew,
                                float* __restrict__ ea) {
  int idx = blockIdx.x * blockDim.x + threadIdx.x;
  if (idx >= N_EDGES * HC) return;
  int e = idx >> 7, c = idx & 127;
  const float* a = eattr + (size_t)e*4;
  const float* w = ew + (size_t)c*4;
  ea[idx] = a[0]*w[0] + a[1]*w[1] + a[2]*w[2] + a[3]*w[3];
}

// ---------------------------------------------------------------------------
// Split-bf16 MFMA GEMM: C[M,N] = epi(A @ B^T + bias) (+resid).
// B pre-split bf16 hi/lo in global; fragments read directly (L2-hot weights).
// Tile 128x128, BK=32, 256 threads. GATHER=1: A = cat(A0, h[src]+h[dst]), K=256.
template<int EPI, int GATHER>
__global__ __launch_bounds__(256, 2) void mgemm(
    const float* A0,
    const unsigned short* __restrict__ Bh, const unsigned short* __restrict__ Bl,
    const float* __restrict__ bias, const float* resid, float* C,
    int M, int K, int N, const int* __restrict__ ei, const float* __restrict__ hgat)
{
  __shared__ unsigned short lds[2 * 128 * 40];   // A hi/lo, pitch 40
  __shared__ int sS[128], sD[128];
  const int AH = 0, AL = 5120;

  const int tid  = threadIdx.x;
  const int m0   = blockIdx.x * 128;
  const int n0   = blockIdx.y * 128;
  const int lane = tid & 63, wave = tid >> 6;
  const int quad = lane >> 4, l16 = lane & 15;
  const int wm = (wave >> 1) * 64, wn = (wave & 1) * 64;
  const int r  = tid >> 1;
  const int c0 = (tid & 1) * 16;

  if (GATHER) {
    if (tid < 128) {
      int e  = m0 + tid;
      int ge = (e < M) ? e : (M - 1);
      sS[tid] = ei[ge];
      sD[tid] = ei[N_EDGES + ge];
    }
  }

  f4v acc[4][4];
  const f4v zf = {0.f, 0.f, 0.f, 0.f};
#pragma unroll
  for (int i = 0; i < 4; i++)
#pragma unroll
    for (int j = 0; j < 4; j++) acc[i][j] = zf;

  const bool mok = (m0 + r) < M;
  const size_t arow = (size_t)(m0 + r);

  __syncthreads();

  for (int kk = 0; kk < K; kk += 32) {
    float av[16];
    const int kg = kk + c0;
    if (!GATHER) {
      if (mok) {
        const float* ap = A0 + arow * K + kg;
#pragma unroll
        for (int q = 0; q < 4; q++) *(float4*)&av[q*4] = *(const float4*)(ap + q*4);
      } else {
#pragma unroll
        for (int j = 0; j < 16; j++) av[j] = 0.f;
      }
    } else {
      if (mok) {
        if (kg < HC) {
          const float* ap = A0 + arow * HC + kg;
#pragma unroll
          for (int q = 0; q < 4; q++) *(float4*)&av[q*4] = *(const float4*)(ap + q*4);
        } else {
          const float* p1 = hgat + (size_t)sS[r] * HC + (kg - HC);
          const float* p2 = hgat + (size_t)sD[r] * HC + (kg - HC);
#pragma unroll
          for (int q = 0; q < 4; q++) {
            float4 xa = *(const float4*)(p1 + q*4);
            float4 xb = *(const float4*)(p2 + q*4);
            av[q*4+0] = xa.x + xb.x; av[q*4+1] = xa.y + xb.y;
            av[q*4+2] = xa.z + xb.z; av[q*4+3] = xa.w + xb.w;
          }
        }
      } else {
#pragma unroll
        for (int j = 0; j < 16; j++) av[j] = 0.f;
      }
    }

    bf16x8 bh[4], bl[4];
#pragma unroll
    for (int nt = 0; nt < 4; nt++) {
      const size_t brow = (size_t)(n0 + wn + nt*16 + l16);
      bh[nt] = *(const bf16x8*)&Bh[brow * K + kk + quad*8];
      bl[nt] = *(const bf16x8*)&Bl[brow * K + kk + quad*8];
    }

    __syncthreads();

    unsigned short th[16], tl[16];
#pragma unroll
    for (int j = 0; j < 16; j++) {
      unsigned short hb = f2bf(av[j]);
      th[j] = hb; tl[j] = f2bf(av[j] - bf2f(hb));
    }
    *(bf16x8*)&lds[AH + r*40 + c0]     = *(bf16x8*)&th[0];
    *(bf16x8*)&lds[AH + r*40 + c0 + 8] = *(bf16x8*)&th[8];
    *(bf16x8*)&lds[AL + r*40 + c0]     = *(bf16x8*)&tl[0];
    *(bf16x8*)&lds[AL + r*40 + c0 + 8] = *(bf16x8*)&tl[8];

    __syncthreads();

    bf16x8 ah[4], al[4];
#pragma unroll
    for (int t = 0; t < 4; t++) {
      const int ra = (wm + t*16 + l16) * 40 + quad * 8;
      ah[t] = *(const bf16x8*)&lds[AH + ra];
      al[t] = *(const bf16x8*)&lds[AL + ra];
    }
#pragma unroll
    for (int mt = 0; mt < 4; mt++)
#pragma unroll
      for (int nt = 0; nt < 4; nt++) {
        acc[mt][nt] = __builtin_amdgcn_mfma_f32_16x16x32_bf16(ah[mt], bh[nt], acc[mt][nt], 0, 0, 0);
        acc[mt][nt] = __builtin_amdgcn_mfma_f32_16x16x32_bf16(ah[mt], bl[nt], acc[mt][nt], 0, 0, 0);
        acc[mt][nt] = __builtin_amdgcn_mfma_f32_16x16x32_bf16(al[mt], bh[nt], acc[mt][nt], 0, 0, 0);
      }
  }

#pragma unroll
  for (int nt = 0; nt < 4; nt++) {
    const int ncol = n0 + wn + nt*16 + l16;
    float bz = 0.f;
    if constexpr (EPI != EPI_NONE) bz = bias[ncol];
#pragma unroll
    for (int mt = 0; mt < 4; mt++) {
      const int mb = wm + mt*16 + quad*4;
#pragma unroll
      for (int rr = 0; rr < 4; rr++) {
        const int m = m0 + mb + rr;
        if (m >= M) continue;
        float v = acc[mt][nt][rr] + bz;
        if constexpr (EPI == EPI_SSP)           v = ssp_f(v);
        else if constexpr (EPI == EPI_RELU_RES) v = fmaxf(v, 0.f);
        else if constexpr (EPI == EPI_TANH_RES) v = tanhf(v);
        if constexpr (EPI == EPI_RELU_RES || EPI == EPI_TANH_RES)
          v += resid[(size_t)m * N + ncol];
        C[(size_t)m * N + ncol] = v;
      }
    }
  }
}

// ---------------------------------------------------------------------------
// Fused lin1 + filter MLP + in-register run-reduced scatter, dst-sorted edges.
// 64-edge tile, 256 threads, LDS 53760 B -> 3 blocks/CU.
// Row-perm trick: physical row r holds edge perm[m0+sigma(r)] so each lane's
// 16 acc rows are contiguous dst-sorted edges (run-reduce in regs).
// R10: lin1 folded in — hacc = (h[src-tile] @ l1w^T) computed via MFMA with
// the SAME C-layout as wacc (rows=edges, cols=NFC), replacing the h1 gather
// (1KB/row) with an h gather (512B/row) and killing the standalone l1 GEMM.
__device__ __forceinline__ int sigma_row(int r) {
  return ((r >> 2) & 3) * 16 + (r >> 4) * 4 + (r & 3);
}
__global__ __launch_bounds__(256, 3) void ffs_kernel(
    const float* __restrict__ ea,
    const unsigned short* __restrict__ l1h, const unsigned short* __restrict__ l1l,
    const unsigned short* __restrict__ fw1h, const unsigned short* __restrict__ fw1l,
    const float* __restrict__ fb1,
    const unsigned short* __restrict__ fw2h, const unsigned short* __restrict__ fw2l,
    const float* __restrict__ fb2, const int* __restrict__ ei,
    const int* __restrict__ perm,
    const float* __restrict__ hfeat, float* agg)
{
  __shared__ unsigned short ldsA[2][64][136];   // ea hi/lo        34816 B
  __shared__ unsigned short ldsT[2][64][72];    // T chunk / h stage 18432 B
  __shared__ int sS[64], sD[64];                //                    512 B

  const int tid  = threadIdx.x;
  const int m0   = blockIdx.x * 64;
  const int lane = tid & 63, wave = tid >> 6;     // wave 0..3
  const int quad = lane >> 4, l16 = lane & 15;

  // stage ea tile 64x128, row-permuted: physical row r <- edge perm[m0+sigma(r)]
  {
    const int r = tid >> 2, cb = (tid & 3) * 32;
    const int pe = perm[m0 + sigma_row(r)];
    const float* ap = ea + (size_t)pe * HC + cb;
    unsigned short th[32], tl[32];
#pragma unroll
    for (int q = 0; q < 8; q++) {
      float4 v = *(const float4*)(ap + q*4);
      float vv[4] = {v.x, v.y, v.z, v.w};
#pragma unroll
      for (int e = 0; e < 4; e++) {
        unsigned short hb = f2bf(vv[e]);
        th[q*4+e] = hb; tl[q*4+e] = f2bf(vv[e] - bf2f(hb));
      }
    }
#pragma unroll
    for (int q = 0; q < 4; q++) {
      *(bf16x8*)&ldsA[0][r][cb + q*8] = *(bf16x8*)&th[q*8];
      *(bf16x8*)&ldsA[1][r][cb + q*8] = *(bf16x8*)&tl[q*8];
    }
  }
  if (tid < 64) {
    int pe = perm[m0 + sigma_row(tid)];
    sS[tid] = ei[pe];
    sD[tid] = ei[N_EDGES + pe];
  }

  const f4v zf = {0.f, 0.f, 0.f, 0.f};
  __syncthreads();   // sS visible; ldsA staged

  // ---- hacc = (h[src-tile] @ l1w^T), C-layout == wacc layout ----
  // h chunks staged split in ldsT region (pitch 40 shorts = 80 B, 16B-aligned).
  f4v hacc[4][4];
#pragma unroll
  for (int mt = 0; mt < 4; mt++)
#pragma unroll
    for (int nt = 0; nt < 4; nt++) hacc[mt][nt] = zf;

  unsigned short* ldsF = &ldsT[0][0][0];   // hi at 0, lo at +2560 shorts
  for (int kk = 0; kk < 128; kk += 32) {
    {
      const int r = tid >> 2, c8 = (tid & 3) * 8;
      const float* hp_ = hfeat + (size_t)sS[r] * HC + kk + c8;
      float4 v0 = *(const float4*)hp_;
      float4 v1 = *(const float4*)(hp_ + 4);
      float vv[8] = {v0.x, v0.y, v0.z, v0.w, v1.x, v1.y, v1.z, v1.w};
      unsigned short th[8], tl[8];
#pragma unroll
      for (int e = 0; e < 8; e++) {
        unsigned short hb = f2bf(vv[e]);
        th[e] = hb; tl[e] = f2bf(vv[e] - bf2f(hb));
      }
      *(bf16x8*)&ldsF[r*40 + c8]        = *(bf16x8*)&th[0];
      *(bf16x8*)&ldsF[2560 + r*40 + c8] = *(bf16x8*)&tl[0];
    }
    __syncthreads();
#pragma unroll
    for (int nt = 0; nt < 4; nt++) {
      const size_t brow = (size_t)(wave*64 + nt*16 + l16);
      bf16x8 bh = *(const bf16x8*)&l1h[brow * HC + kk + quad*8];
      bf16x8 bl = *(const bf16x8*)&l1l[brow * HC + kk + quad*8];
#pragma unroll
      for (int mt = 0; mt < 4; mt++) {
        bf16x8 ah = *(const bf16x8*)&ldsF[(mt*16 + l16)*40 + quad*8];
        bf16x8 al = *(const bf16x8*)&ldsF[2560 + (mt*16 + l16)*40 + quad*8];
        hacc[mt][nt] = __builtin_amdgcn_mfma_f32_16x16x32_bf16(ah, bh, hacc[mt][nt], 0, 0, 0);
        hacc[mt][nt] = __builtin_amdgcn_mfma_f32_16x16x32_bf16(ah, bl, hacc[mt][nt], 0, 0, 0);
        hacc[mt][nt] = __builtin_amdgcn_mfma_f32_16x16x32_bf16(al, bh, hacc[mt][nt], 0, 0, 0);
      }
    }
    __syncthreads();
  }

  f4v wacc[4][4];
#pragma unroll
  for (int mt = 0; mt < 4; mt++)
#pragma unroll
    for (int nt = 0; nt < 4; nt++) wacc[mt][nt] = zf;

  for (int p = 0; p < 4; p++) {
    // ---- GEMM1: T_p[64,64]; wave owns COLS (fw1 fragments wave-distinct) ----
    f4v tacc[4];
#pragma unroll
    for (int mt = 0; mt < 4; mt++) tacc[mt] = zf;
    const size_t b1row = (size_t)(p*64 + wave*16 + l16);
#pragma unroll
    for (int kk = 0; kk < 128; kk += 32) {
      bf16x8 bh = *(const bf16x8*)&fw1h[b1row * HC + kk + quad*8];
      bf16x8 bl = *(const bf16x8*)&fw1l[b1row * HC + kk + quad*8];
#pragma unroll
      for (int mt = 0; mt < 4; mt++) {
        bf16x8 ah = *(const bf16x8*)&ldsA[0][mt*16 + l16][kk + quad*8];
        bf16x8 al = *(const bf16x8*)&ldsA[1][mt*16 + l16][kk + quad*8];
        tacc[mt] = __builtin_amdgcn_mfma_f32_16x16x32_bf16(ah, bh, tacc[mt], 0, 0, 0);
        tacc[mt] = __builtin_amdgcn_mfma_f32_16x16x32_bf16(ah, bl, tacc[mt], 0, 0, 0);
        tacc[mt] = __builtin_amdgcn_mfma_f32_16x16x32_bf16(al, bh, tacc[mt], 0, 0, 0);
      }
    }
    // ssp + split -> T LDS (C layout: col = wave*16+l16, row = mt*16+quad*4+rr)
    {
      const int col = wave*16 + l16;
      const float bz = fb1[p*64 + col];
#pragma unroll
      for (int mt = 0; mt < 4; mt++) {
        const int rowb = mt*16 + quad*4;
#pragma unroll
        for (int rr = 0; rr < 4; rr++) {
          float v = ssp_f(tacc[mt][rr] + bz);
          unsigned short hb = f2bf(v);
          ldsT[0][rowb+rr][col] = hb;
          ldsT[1][rowb+rr][col] = f2bf(v - bf2f(hb));
        }
      }
    }
    __syncthreads();

    // ---- GEMM2 partial: W += T_p @ fw2[:, p*64..+64]^T (B wave-distinct) ----
#pragma unroll
    for (int kc = 0; kc < 2; kc++) {
      bf16x8 a_h[4], a_l[4];
#pragma unroll
      for (int mt = 0; mt < 4; mt++) {
        a_h[mt] = *(const bf16x8*)&ldsT[0][mt*16 + l16][kc*32 + quad*8];
        a_l[mt] = *(const bf16x8*)&ldsT[1][mt*16 + l16][kc*32 + quad*8];
      }
#pragma unroll
      for (int nt = 0; nt < 4; nt++) {
        const size_t brow = (size_t)(wave*64 + nt*16 + l16);
        bf16x8 bh = *(const bf16x8*)&fw2h[brow * NFC + p*64 + kc*32 + quad*8];
        bf16x8 bl = *(const bf16x8*)&fw2l[brow * NFC + p*64 + kc*32 + quad*8];
#pragma unroll
        for (int mt = 0; mt < 4; mt++) {
          wacc[mt][nt] = __builtin_amdgcn_mfma_f32_16x16x32_bf16(a_h[mt], bh, wacc[mt][nt], 0, 0, 0);
          wacc[mt][nt] = __builtin_amdgcn_mfma_f32_16x16x32_bf16(a_h[mt], bl, wacc[mt][nt], 0, 0, 0);
          wacc[mt][nt] = __builtin_amdgcn_mfma_f32_16x16x32_bf16(a_l[mt], bh, wacc[mt][nt], 0, 0, 0);
        }
      }
    }
    __syncthreads();   // T reads done before next phase overwrites
  }

  // ---- in-register run-reduced scatter: v = (W+b2) * hj, hj from hacc ----
#pragma unroll
  for (int nt = 0; nt < 4; nt++) {
    const int col = wave*64 + nt*16 + l16;
    const float bz = fb2[col];
    float accum = 0.f;
    int prev = -1;
#pragma unroll
    for (int mt = 0; mt < 4; mt++) {
#pragma unroll
      for (int rr = 0; rr < 4; rr++) {
        const int prow = mt*16 + quad*4 + rr;
        const int d = sD[prow];
        const float v = (wacc[mt][nt][rr] + bz) * hacc[mt][nt][rr];
        if (d != prev) {
          if (prev >= 0) atomicAdd(&agg[(size_t)prev * NFC + col], accum);
          accum = v; prev = d;
        } else {
          accum += v;
        }
      }
    }
    atomicAdd(&agg[(size_t)prev * NFC + col], accum);
  }
}

// ---------------------------------------------------------------------------
__global__ void pool_kernel(const int* __restrict__ batch, const float* __restrict__ h,
                            float* __restrict__ ssum, float* __restrict__ cnt) {
  int idx = blockIdx.x * blockDim.x + threadIdx.x;
  if (idx >= N_NODES * HC) return;
  int n = idx >> 7, c = idx & 127;
  int b = batch[n];
  atomicAdd(&ssum[(size_t)b*HC + c], h[idx]);
  if (c == 0) atomicAdd(&cnt[b], 1.0f);
}

__global__ __launch_bounds__(256) void head_kernel(
    const float* __restrict__ ssum, const float* __restrict__ cnt,
    const float* __restrict__ w1, const float* __restrict__ b1,
    const float* __restrict__ w2, const float* __restrict__ b2,
    float* __restrict__ y) {
  int g = blockIdx.x;
  __shared__ float gs[HC];
  __shared__ float red[256];
  int tid = threadIdx.x;
  float inv = 1.0f / fmaxf(cnt[g], 1.0f);
  if (tid < HC) gs[tid] = ssum[(size_t)g*HC + tid] * inv;
  __syncthreads();
  float partial = 0.0f;
  for (int f = tid; f < NFFC; f += 256) {
    float acc = b1[f];
    const float* wr = w1 + (size_t)f*HC;
#pragma unroll 8
    for (int k = 0; k < HC; k++) acc = fmaf(gs[k], wr[k], acc);
    float t = 0.5f * acc * (1.0f + erff(acc * 0.70710678118654752440f));
    partial = fmaf(t, w2[f], partial);
  }
  red[tid] = partial;
  __syncthreads();
  for (int s = 128; s > 0; s >>= 1) {
    if (tid < s) red[tid] += red[tid + s];
    __syncthreads();
  }
  if (tid == 0) y[g] = red[0] + b2[0];
}

// ---------------------------------------------------------------------------
extern "C" void kernel_launch(void* const* d_in, const int* in_sizes, int n_in,
                              void* d_out, int out_size, void* d_ws, size_t ws_size,
                              hipStream_t stream) {
  const int*   x     = (const int*)  d_in[0];
  const int*   ei    = (const int*)  d_in[1];
  const float* eattr = (const float*)d_in[2];
  const int*   batch = (const int*)  d_in[3];
  const float* pos   = (const float*)d_in[4];
  const float* vert  = (const float*)d_in[5];
  const float* posw  = (const float*)d_in[6];
  const float* edgew = (const float*)d_in[7];
  const float* fw1   = (const float*)d_in[8];
  const float* fb1   = (const float*)d_in[9];
  const float* fw2   = (const float*)d_in[10];
  const float* fb2   = (const float*)d_in[11];
  const float* l1w   = (const float*)d_in[12];
  const float* l2w   = (const float*)d_in[13];
  const float* l2b   = (const float*)d_in[14];
  const float* l3w   = (const float*)d_in[15];
  const float* l3b   = (const float*)d_in[16];
  const float* emw   = (const float*)d_in[17];
  const float* emb   = (const float*)d_in[18];
  const float* hw1   = (const float*)d_in[19];
  const float* hb1   = (const float*)d_in[20];
  const float* hw2   = (const float*)d_in[21];
  const float* hb2   = (const float*)d_in[22];
  float* out = (float*)d_out;

  char* ws = (char*)d_ws;
  size_t off = 0;
  auto alloc = [&](size_t bytes) { char* p = ws + off; off += (bytes + 511) & ~(size_t)511; return p; };
  float* ea   = (float*)alloc((size_t)N_EDGES*HC*4);
  float* h    = (float*)alloc((size_t)N_NODES*HC*4);
  float* t2   = (float*)alloc((size_t)N_NODES*NFC*4);   // ssp(agg@l2^T) out
  float* agg  = (float*)alloc((size_t)N_NODES*NFC*4);
  float* ssum = (float*)alloc((size_t)N_GRAPH*HC*4);
  float* cnt  = (float*)alloc((size_t)N_GRAPH*4);
  int* deg    = (int*)alloc((size_t)(N_NODES+1)*4);
  int* cursor = (int*)alloc((size_t)(N_NODES+1)*4);
  int* perm   = (int*)alloc((size_t)N_EDGES*4);
  const int n_fw1 = NLAYER*NFC*HC, n_fw2 = NLAYER*NFC*NFC, n_l1 = NLAYER*NFC*HC;
  const int n_l2 = NLAYER*HC*NFC, n_l3 = NLAYER*HC*HC, n_em = NLAYER*HC*2*HC;
  unsigned short* fw1h = (unsigned short*)alloc((size_t)n_fw1*2);
  unsigned short* fw1l = (unsigned short*)alloc((size_t)n_fw1*2);
  unsigned short* fw2h = (unsigned short*)alloc((size_t)n_fw2*2);
  unsigned short* fw2l = (unsigned short*)alloc((size_t)n_fw2*2);
  unsigned short* l1h  = (unsigned short*)alloc((size_t)n_l1*2);
  unsigned short* l1l  = (unsigned short*)alloc((size_t)n_l1*2);
  unsigned short* l2h  = (unsigned short*)alloc((size_t)n_l2*2);
  unsigned short* l2l  = (unsigned short*)alloc((size_t)n_l2*2);
  unsigned short* l3h  = (unsigned short*)alloc((size_t)n_l3*2);
  unsigned short* l3l  = (unsigned short*)alloc((size_t)n_l3*2);
  unsigned short* emh  = (unsigned short*)alloc((size_t)n_em*2);
  unsigned short* eml  = (unsigned short*)alloc((size_t)n_em*2);

  zeroi_kernel<<<(N_NODES+1+255)/256, 256, 0, stream>>>(deg, N_NODES+1);
  hist_kernel<<<(N_EDGES+255)/256, 256, 0, stream>>>(ei, deg);
  scan_kernel<<<1, 1024, 0, stream>>>(deg, cursor, N_NODES+1);
  perm_kernel<<<(N_EDGES+255)/256, 256, 0, stream>>>(ei, cursor, perm);

  wsplit_kernel<<<(n_fw1+255)/256, 256, 0, stream>>>(fw1, fw1h, fw1l, n_fw1);
  wsplit_kernel<<<(n_fw2+255)/256, 256, 0, stream>>>(fw2, fw2h, fw2l, n_fw2);
  wsplit_kernel<<<(n_l1 +255)/256, 256, 0, stream>>>(l1w, l1h, l1l, n_l1);
  wsplit_kernel<<<(n_l2 +255)/256, 256, 0, stream>>>(l2w, l2h, l2l, n_l2);
  wsplit_kernel<<<(n_l3 +255)/256, 256, 0, stream>>>(l3w, l3h, l3l, n_l3);
  wsplit_kernel<<<(n_em +255)/256, 256, 0, stream>>>(emw, emh, eml, n_em);

  const int GN   = (N_NODES + 127) / 128;   // 391
  const int GE   = (N_EDGES + 127) / 128;   // 1563
  const int GE64 = N_EDGES / 64;            // 3125 (exact)

  embed_kernel<<<N_NODES, 128, 0, stream>>>(x, pos, vert, posw, h);
  edgeproj_kernel<<<(N_EDGES*HC + 255)/256, 256, 0, stream>>>(eattr, edgew, ea);

  for (int i = 0; i < NLAYER; ++i) {
    zero_kernel<<<((N_NODES*NFC/4) + 255)/256, 256, 0, stream>>>(
        (float4*)agg, N_NODES*NFC/4);
    // fused lin1 + filter MLP + scatter
    ffs_kernel<<<GE64, 256, 0, stream>>>(
        ea, l1h + (size_t)i*NFC*HC, l1l + (size_t)i*NFC*HC,
        fw1h + (size_t)i*NFC*HC, fw1l + (size_t)i*NFC*HC, fb1 + (size_t)i*NFC,
        fw2h + (size_t)i*NFC*NFC, fw2l + (size_t)i*NFC*NFC, fb2 + (size_t)i*NFC,
        ei, perm, h, agg);
    mgemm<EPI_SSP,0><<<dim3(GN,1), 256, 0, stream>>>(
        agg, l2h + (size_t)i*HC*NFC, l2l + (size_t)i*HC*NFC, l2b + (size_t)i*HC,
        nullptr, t2, N_NODES, NFC, HC, nullptr, nullptr);
    mgemm<EPI_RELU_RES,0><<<dim3(GN,1), 256, 0, stream>>>(
        t2, l3h + (size_t)i*HC*HC, l3l + (size_t)i*HC*HC, l3b + (size_t)i*HC,
        h, h, N_NODES, HC, HC, nullptr, nullptr);
    mgemm<EPI_TANH_RES,1><<<dim3(GE,1), 256, 0, stream>>>(
        ea, emh + (size_t)i*HC*2*HC, eml + (size_t)i*HC*2*HC, emb + (size_t)i*HC,
        ea, ea, N_EDGES, 2*HC, HC, ei, h);
  }

  zero_kernel<<<((N_GRAPH*HC/4) + 255)/256, 256, 0, stream>>>((float4*)ssum, N_GRAPH*HC/4);
  zero_kernel<<<((N_GRAPH/4) + 255)/256, 256, 0, stream>>>((float4*)cnt, N_GRAPH/4);
  pool_kernel<<<(N_NODES*HC + 255)/256, 256, 0, stream>>>(batch, h, ssum, cnt);
  head_kernel<<<N_GRAPH, 256, 0, stream>>>(ssum, cnt, hw1, hb1, hw2, hb2, out);
}

// Round 11
// 2658.876 us; speedup vs baseline: 1.6293x; 1.2492x over previous
//
#include <hip/hip_runtime.h>
#include <hip/hip_bf16.h>
#include <math.h>

#define N_NODES 50000
#define N_EDGES 200000
#define N_GRAPH 1024
#define HC      128
#define NFC     256
#define NLAYER  5
#define NFFC    512

enum { EPI_NONE=0, EPI_SSP=2, EPI_RELU_RES=3, EPI_TANH_RES=4 };

typedef short bf16x8 __attribute__((ext_vector_type(8)));
typedef float f4v    __attribute__((ext_vector_type(4)));

// fast ssp: softplus(x)-ln2 via v_exp/v_log (~1e-7 abs err)
__device__ __forceinline__ float ssp_f(float x) {
  float e = __expf(-fabsf(x));
  return fmaxf(x, 0.0f) + __logf(1.0f + e) - 0.69314718055994530942f;
}
// fast tanh via v_exp + v_rcp (~1e-6 err); overflow-safe (exp->inf -> t->1)
__device__ __forceinline__ float tanh_f(float x) {
  float e = __expf(2.0f * fabsf(x));
  float t = 1.0f - 2.0f * __builtin_amdgcn_rcpf(e + 1.0f);
  return copysignf(t, x);
}
__device__ __forceinline__ unsigned short f2bf(float x) {
  union { float f; unsigned u; } v; v.f = x;
  unsigned r = v.u + 0x7fff + ((v.u >> 16) & 1);
  return (unsigned short)(r >> 16);
}
__device__ __forceinline__ float bf2f(unsigned short b) {
  union { unsigned u; float f; } v; v.u = (unsigned)b << 16; return v.f;
}

// ---------------------------------------------------------------------------
__global__ void zero_kernel(float4* __restrict__ p, int n4) {
  int i = blockIdx.x * blockDim.x + threadIdx.x;
  if (i < n4) p[i] = make_float4(0.f, 0.f, 0.f, 0.f);
}
__global__ void zeroi_kernel(int* __restrict__ p, int n) {
  int i = blockIdx.x * blockDim.x + threadIdx.x;
  if (i < n) p[i] = 0;
}

// ---- dst-sort infrastructure (ei fixed input; rebuilt every call) ----------
__global__ void hist_kernel(const int* __restrict__ ei, int* __restrict__ deg) {
  int e = blockIdx.x * blockDim.x + threadIdx.x;
  if (e < N_EDGES) atomicAdd(&deg[ei[N_EDGES + e]], 1);
}
__global__ __launch_bounds__(1024) void scan_kernel(
    const int* __restrict__ deg, int* __restrict__ cursor, int n) {
  __shared__ int buf[1024];
  __shared__ int carry;
  if (threadIdx.x == 0) carry = 0;
  __syncthreads();
  for (int base = 0; base < n; base += 1024) {
    int i = base + threadIdx.x;
    int v = (i < n) ? deg[i] : 0;
    buf[threadIdx.x] = v;
    __syncthreads();
    for (int s = 1; s < 1024; s <<= 1) {
      int t = (threadIdx.x >= s) ? buf[threadIdx.x - s] : 0;
      __syncthreads();
      buf[threadIdx.x] += t;
      __syncthreads();
    }
    int excl = carry + buf[threadIdx.x] - v;
    if (i < n) cursor[i] = excl;
    int tot = buf[1023];
    __syncthreads();
    if (threadIdx.x == 0) carry += tot;
    __syncthreads();
  }
}
__global__ void perm_kernel(const int* __restrict__ ei, int* __restrict__ cursor,
                            int* __restrict__ perm) {
  int e = blockIdx.x * blockDim.x + threadIdx.x;
  if (e < N_EDGES) {
    int d = ei[N_EDGES + e];
    int p = atomicAdd(&cursor[d], 1);
    perm[p] = e;
  }
}

// split fp32 weights -> bf16 hi + lo
__global__ void wsplit_kernel(const float* __restrict__ w,
                              unsigned short* __restrict__ hi,
                              unsigned short* __restrict__ lo, int n) {
  int i = blockIdx.x * blockDim.x + threadIdx.x;
  if (i < n) {
    float v = w[i];
    unsigned short hb = f2bf(v);
    hi[i] = hb;
    lo[i] = f2bf(v - bf2f(hb));
  }
}

__global__ void embed_kernel(const int* __restrict__ x, const float* __restrict__ pos,
                             const float* __restrict__ vert, const float* __restrict__ posw,
                             float* __restrict__ h) {
  int n = blockIdx.x;
  int c = threadIdx.x;            // 128 threads
  float v;
  if (c < 80) {
    v = vert[(size_t)x[n] * 80 + c];
  } else {
    int j = c - 80;
    v = pos[n*3+0]*posw[j*3+0] + pos[n*3+1]*posw[j*3+1] + pos[n*3+2]*posw[j*3+2];
  }
  h[(size_t)n*HC + c] = v;
}

__global__ void edgeproj_kernel(const float* __restrict__ eattr, const float* __restrict__ ew,
                                float* __restrict__ ea) {
  int idx = blockIdx.x * blockDim.x + threadIdx.x;
  if (idx >= N_EDGES * HC) return;
  int e = idx >> 7, c = idx & 127;
  const float* a = eattr + (size_t)e*4;
  const float* w = ew + (size_t)c*4;
  ea[idx] = a[0]*w[0] + a[1]*w[1] + a[2]*w[2] + a[3]*w[3];
}

// ---------------------------------------------------------------------------
// Split-bf16 MFMA GEMM (used for edge-MLP only): C=epi(A@B^T+bias)(+resid).
// GATHER=1: A = cat(A0, h[src]+h[dst]), K=256.
template<int EPI, int GATHER>
__global__ __launch_bounds__(256, 2) void mgemm(
    const float* A0,
    const unsigned short* __restrict__ Bh, const unsigned short* __restrict__ Bl,
    const float* __restrict__ bias, const float* resid, float* C,
    int M, int K, int N, const int* __restrict__ ei, const float* __restrict__ hgat)
{
  __shared__ unsigned short lds[2 * 128 * 40];   // A hi/lo, pitch 40
  __shared__ int sS[128], sD[128];
  const int AH = 0, AL = 5120;

  const int tid  = threadIdx.x;
  const int m0   = blockIdx.x * 128;
  const int n0   = blockIdx.y * 128;
  const int lane = tid & 63, wave = tid >> 6;
  const int quad = lane >> 4, l16 = lane & 15;
  const int wm = (wave >> 1) * 64, wn = (wave & 1) * 64;
  const int r  = tid >> 1;
  const int c0 = (tid & 1) * 16;

  if (GATHER) {
    if (tid < 128) {
      int e  = m0 + tid;
      int ge = (e < M) ? e : (M - 1);
      sS[tid] = ei[ge];
      sD[tid] = ei[N_EDGES + ge];
    }
  }

  f4v acc[4][4];
  const f4v zf = {0.f, 0.f, 0.f, 0.f};
#pragma unroll
  for (int i = 0; i < 4; i++)
#pragma unroll
    for (int j = 0; j < 4; j++) acc[i][j] = zf;

  const bool mok = (m0 + r) < M;
  const size_t arow = (size_t)(m0 + r);

  __syncthreads();

  for (int kk = 0; kk < K; kk += 32) {
    float av[16];
    const int kg = kk + c0;
    if (!GATHER) {
      if (mok) {
        const float* ap = A0 + arow * K + kg;
#pragma unroll
        for (int q = 0; q < 4; q++) *(float4*)&av[q*4] = *(const float4*)(ap + q*4);
      } else {
#pragma unroll
        for (int j = 0; j < 16; j++) av[j] = 0.f;
      }
    } else {
      if (mok) {
        if (kg < HC) {
          const float* ap = A0 + arow * HC + kg;
#pragma unroll
          for (int q = 0; q < 4; q++) *(float4*)&av[q*4] = *(const float4*)(ap + q*4);
        } else {
          const float* p1 = hgat + (size_t)sS[r] * HC + (kg - HC);
          const float* p2 = hgat + (size_t)sD[r] * HC + (kg - HC);
#pragma unroll
          for (int q = 0; q < 4; q++) {
            float4 xa = *(const float4*)(p1 + q*4);
            float4 xb = *(const float4*)(p2 + q*4);
            av[q*4+0] = xa.x + xb.x; av[q*4+1] = xa.y + xb.y;
            av[q*4+2] = xa.z + xb.z; av[q*4+3] = xa.w + xb.w;
          }
        }
      } else {
#pragma unroll
        for (int j = 0; j < 16; j++) av[j] = 0.f;
      }
    }

    bf16x8 bh[4], bl[4];
#pragma unroll
    for (int nt = 0; nt < 4; nt++) {
      const size_t brow = (size_t)(n0 + wn + nt*16 + l16);
      bh[nt] = *(const bf16x8*)&Bh[brow * K + kk + quad*8];
      bl[nt] = *(const bf16x8*)&Bl[brow * K + kk + quad*8];
    }

    __syncthreads();

    unsigned short th[16], tl[16];
#pragma unroll
    for (int j = 0; j < 16; j++) {
      unsigned short hb = f2bf(av[j]);
      th[j] = hb; tl[j] = f2bf(av[j] - bf2f(hb));
    }
    *(bf16x8*)&lds[AH + r*40 + c0]     = *(bf16x8*)&th[0];
    *(bf16x8*)&lds[AH + r*40 + c0 + 8] = *(bf16x8*)&th[8];
    *(bf16x8*)&lds[AL + r*40 + c0]     = *(bf16x8*)&tl[0];
    *(bf16x8*)&lds[AL + r*40 + c0 + 8] = *(bf16x8*)&tl[8];

    __syncthreads();

    bf16x8 ah[4], al[4];
#pragma unroll
    for (int t = 0; t < 4; t++) {
      const int ra = (wm + t*16 + l16) * 40 + quad * 8;
      ah[t] = *(const bf16x8*)&lds[AH + ra];
      al[t] = *(const bf16x8*)&lds[AL + ra];
    }
#pragma unroll
    for (int mt = 0; mt < 4; mt++)
#pragma unroll
      for (int nt = 0; nt < 4; nt++) {
        acc[mt][nt] = __builtin_amdgcn_mfma_f32_16x16x32_bf16(ah[mt], bh[nt], acc[mt][nt], 0, 0, 0);
        acc[mt][nt] = __builtin_amdgcn_mfma_f32_16x16x32_bf16(ah[mt], bl[nt], acc[mt][nt], 0, 0, 0);
        acc[mt][nt] = __builtin_amdgcn_mfma_f32_16x16x32_bf16(al[mt], bh[nt], acc[mt][nt], 0, 0, 0);
      }
  }

#pragma unroll
  for (int nt = 0; nt < 4; nt++) {
    const int ncol = n0 + wn + nt*16 + l16;
    float bz = 0.f;
    if constexpr (EPI != EPI_NONE) bz = bias[ncol];
#pragma unroll
    for (int mt = 0; mt < 4; mt++) {
      const int mb = wm + mt*16 + quad*4;
#pragma unroll
      for (int rr = 0; rr < 4; rr++) {
        const int m = m0 + mb + rr;
        if (m >= M) continue;
        float v = acc[mt][nt][rr] + bz;
        if constexpr (EPI == EPI_SSP)           v = ssp_f(v);
        else if constexpr (EPI == EPI_RELU_RES) v = fmaxf(v, 0.f);
        else if constexpr (EPI == EPI_TANH_RES) v = tanh_f(v);
        if constexpr (EPI == EPI_RELU_RES || EPI == EPI_TANH_RES)
          v += resid[(size_t)m * N + ncol];
        C[(size_t)m * N + ncol] = v;
      }
    }
  }
}

// ---------------------------------------------------------------------------
// Fused node update: h = relu(ssp(agg @ l2^T + b2) @ l3^T + b3) + h.
// t2 lives only in LDS (split bf16, pitch 136). 128-node tile, 256 threads.
__global__ __launch_bounds__(256, 2) void nodeup_kernel(
    const float* __restrict__ agg,
    const unsigned short* __restrict__ L2h, const unsigned short* __restrict__ L2l,
    const float* __restrict__ b2,
    const unsigned short* __restrict__ L3h, const unsigned short* __restrict__ L3l,
    const float* __restrict__ b3,
    float* h)
{
  __shared__ unsigned short lds[2 * 128 * 136];   // 69632 B (A-stage region reused for t2)
  const int AH = 0, AL = 5120;            // A chunk staging (pitch 40)
  const int TH = 0, TL = 17408;           // t2 full tile (pitch 136)

  const int tid  = threadIdx.x;
  const int m0   = blockIdx.x * 128;
  const int lane = tid & 63, wave = tid >> 6;
  const int quad = lane >> 4, l16 = lane & 15;
  const int wm = (wave >> 1) * 64, wn = (wave & 1) * 64;
  const int r  = tid >> 1;
  const int c0 = (tid & 1) * 16;

  const f4v zf = {0.f, 0.f, 0.f, 0.f};
  f4v acc[4][4];
#pragma unroll
  for (int i = 0; i < 4; i++)
#pragma unroll
    for (int j = 0; j < 4; j++) acc[i][j] = zf;

  const bool mok = (m0 + r) < N_NODES;
  const size_t arow = (size_t)(m0 + r);

  // ---- GEMM1: t2acc = agg @ l2^T (K=256) ----
  for (int kk = 0; kk < NFC; kk += 32) {
    float av[16];
    if (mok) {
      const float* ap = agg + arow * NFC + kk + c0;
#pragma unroll
      for (int q = 0; q < 4; q++) *(float4*)&av[q*4] = *(const float4*)(ap + q*4);
    } else {
#pragma unroll
      for (int j = 0; j < 16; j++) av[j] = 0.f;
    }
    bf16x8 bh[4], bl[4];
#pragma unroll
    for (int nt = 0; nt < 4; nt++) {
      const size_t brow = (size_t)(wn + nt*16 + l16);
      bh[nt] = *(const bf16x8*)&L2h[brow * NFC + kk + quad*8];
      bl[nt] = *(const bf16x8*)&L2l[brow * NFC + kk + quad*8];
    }
    __syncthreads();
    unsigned short th[16], tl[16];
#pragma unroll
    for (int j = 0; j < 16; j++) {
      unsigned short hb = f2bf(av[j]);
      th[j] = hb; tl[j] = f2bf(av[j] - bf2f(hb));
    }
    *(bf16x8*)&lds[AH + r*40 + c0]     = *(bf16x8*)&th[0];
    *(bf16x8*)&lds[AH + r*40 + c0 + 8] = *(bf16x8*)&th[8];
    *(bf16x8*)&lds[AL + r*40 + c0]     = *(bf16x8*)&tl[0];
    *(bf16x8*)&lds[AL + r*40 + c0 + 8] = *(bf16x8*)&tl[8];
    __syncthreads();
    bf16x8 ah[4], al[4];
#pragma unroll
    for (int t = 0; t < 4; t++) {
      const int ra = (wm + t*16 + l16) * 40 + quad * 8;
      ah[t] = *(const bf16x8*)&lds[AH + ra];
      al[t] = *(const bf16x8*)&lds[AL + ra];
    }
#pragma unroll
    for (int mt = 0; mt < 4; mt++)
#pragma unroll
      for (int nt = 0; nt < 4; nt++) {
        acc[mt][nt] = __builtin_amdgcn_mfma_f32_16x16x32_bf16(ah[mt], bh[nt], acc[mt][nt], 0, 0, 0);
        acc[mt][nt] = __builtin_amdgcn_mfma_f32_16x16x32_bf16(ah[mt], bl[nt], acc[mt][nt], 0, 0, 0);
        acc[mt][nt] = __builtin_amdgcn_mfma_f32_16x16x32_bf16(al[mt], bh[nt], acc[mt][nt], 0, 0, 0);
      }
  }
  __syncthreads();   // all A-region reads complete before t2 overwrite

  // ---- t2 = ssp(acc + b2) -> split LDS (pitch 136) ----
#pragma unroll
  for (int nt = 0; nt < 4; nt++) {
    const int col = wn + nt*16 + l16;
    const float bz = b2[col];
#pragma unroll
    for (int mt = 0; mt < 4; mt++) {
      const int rowb = wm + mt*16 + quad*4;
#pragma unroll
      for (int rr = 0; rr < 4; rr++) {
        float v = ssp_f(acc[mt][nt][rr] + bz);
        unsigned short hb = f2bf(v);
        lds[TH + (rowb+rr)*136 + col] = hb;
        lds[TL + (rowb+rr)*136 + col] = f2bf(v - bf2f(hb));
      }
    }
  }
  __syncthreads();

  // ---- GEMM2: acc2 = t2 @ l3^T (K=128), epilogue relu + residual ----
  f4v acc2[4][4];
#pragma unroll
  for (int i = 0; i < 4; i++)
#pragma unroll
    for (int j = 0; j < 4; j++) acc2[i][j] = zf;

  for (int kk = 0; kk < HC; kk += 32) {
    bf16x8 bh[4], bl[4];
#pragma unroll
    for (int nt = 0; nt < 4; nt++) {
      const size_t brow = (size_t)(wn + nt*16 + l16);
      bh[nt] = *(const bf16x8*)&L3h[brow * HC + kk + quad*8];
      bl[nt] = *(const bf16x8*)&L3l[brow * HC + kk + quad*8];
    }
    bf16x8 ah[4], al[4];
#pragma unroll
    for (int t = 0; t < 4; t++) {
      const int ra = (wm + t*16 + l16) * 136 + kk + quad * 8;
      ah[t] = *(const bf16x8*)&lds[TH + ra];
      al[t] = *(const bf16x8*)&lds[TL + ra];
    }
#pragma unroll
    for (int mt = 0; mt < 4; mt++)
#pragma unroll
      for (int nt = 0; nt < 4; nt++) {
        acc2[mt][nt] = __builtin_amdgcn_mfma_f32_16x16x32_bf16(ah[mt], bh[nt], acc2[mt][nt], 0, 0, 0);
        acc2[mt][nt] = __builtin_amdgcn_mfma_f32_16x16x32_bf16(ah[mt], bl[nt], acc2[mt][nt], 0, 0, 0);
        acc2[mt][nt] = __builtin_amdgcn_mfma_f32_16x16x32_bf16(al[mt], bh[nt], acc2[mt][nt], 0, 0, 0);
      }
  }

#pragma unroll
  for (int nt = 0; nt < 4; nt++) {
    const int ncol = wn + nt*16 + l16;
    const float bz = b3[ncol];
#pragma unroll
    for (int mt = 0; mt < 4; mt++) {
      const int mb = wm + mt*16 + quad*4;
#pragma unroll
      for (int rr = 0; rr < 4; rr++) {
        const int m = m0 + mb + rr;
        if (m < N_NODES) {
          const size_t idx = (size_t)m * HC + ncol;
          h[idx] = fmaxf(acc2[mt][nt][rr] + bz, 0.f) + h[idx];
        }
      }
    }
  }
}

// ---------------------------------------------------------------------------
// Fused lin1 + filter MLP + in-register run-reduced scatter, dst-sorted edges.
// (unchanged from R10 except fast ssp_f)
__device__ __forceinline__ int sigma_row(int r) {
  return ((r >> 2) & 3) * 16 + (r >> 4) * 4 + (r & 3);
}
__global__ __launch_bounds__(256, 3) void ffs_kernel(
    const float* __restrict__ ea,
    const unsigned short* __restrict__ l1h, const unsigned short* __restrict__ l1l,
    const unsigned short* __restrict__ fw1h, const unsigned short* __restrict__ fw1l,
    const float* __restrict__ fb1,
    const unsigned short* __restrict__ fw2h, const unsigned short* __restrict__ fw2l,
    const float* __restrict__ fb2, const int* __restrict__ ei,
    const int* __restrict__ perm,
    const float* __restrict__ hfeat, float* agg)
{
  __shared__ unsigned short ldsA[2][64][136];
  __shared__ unsigned short ldsT[2][64][72];
  __shared__ int sS[64], sD[64];

  const int tid  = threadIdx.x;
  const int m0   = blockIdx.x * 64;
  const int lane = tid & 63, wave = tid >> 6;
  const int quad = lane >> 4, l16 = lane & 15;

  {
    const int r = tid >> 2, cb = (tid & 3) * 32;
    const int pe = perm[m0 + sigma_row(r)];
    const float* ap = ea + (size_t)pe * HC + cb;
    unsigned short th[32], tl[32];
#pragma unroll
    for (int q = 0; q < 8; q++) {
      float4 v = *(const float4*)(ap + q*4);
      float vv[4] = {v.x, v.y, v.z, v.w};
#pragma unroll
      for (int e = 0; e < 4; e++) {
        unsigned short hb = f2bf(vv[e]);
        th[q*4+e] = hb; tl[q*4+e] = f2bf(vv[e] - bf2f(hb));
      }
    }
#pragma unroll
    for (int q = 0; q < 4; q++) {
      *(bf16x8*)&ldsA[0][r][cb + q*8] = *(bf16x8*)&th[q*8];
      *(bf16x8*)&ldsA[1][r][cb + q*8] = *(bf16x8*)&tl[q*8];
    }
  }
  if (tid < 64) {
    int pe = perm[m0 + sigma_row(tid)];
    sS[tid] = ei[pe];
    sD[tid] = ei[N_EDGES + pe];
  }

  const f4v zf = {0.f, 0.f, 0.f, 0.f};
  __syncthreads();

  f4v hacc[4][4];
#pragma unroll
  for (int mt = 0; mt < 4; mt++)
#pragma unroll
    for (int nt = 0; nt < 4; nt++) hacc[mt][nt] = zf;

  unsigned short* ldsF = &ldsT[0][0][0];
  for (int kk = 0; kk < 128; kk += 32) {
    {
      const int r = tid >> 2, c8 = (tid & 3) * 8;
      const float* hp_ = hfeat + (size_t)sS[r] * HC + kk + c8;
      float4 v0 = *(const float4*)hp_;
      float4 v1 = *(const float4*)(hp_ + 4);
      float vv[8] = {v0.x, v0.y, v0.z, v0.w, v1.x, v1.y, v1.z, v1.w};
      unsigned short th[8], tl[8];
#pragma unroll
      for (int e = 0; e < 8; e++) {
        unsigned short hb = f2bf(vv[e]);
        th[e] = hb; tl[e] = f2bf(vv[e] - bf2f(hb));
      }
      *(bf16x8*)&ldsF[r*40 + c8]        = *(bf16x8*)&th[0];
      *(bf16x8*)&ldsF[2560 + r*40 + c8] = *(bf16x8*)&tl[0];
    }
    __syncthreads();
#pragma unroll
    for (int nt = 0; nt < 4; nt++) {
      const size_t brow = (size_t)(wave*64 + nt*16 + l16);
      bf16x8 bh = *(const bf16x8*)&l1h[brow * HC + kk + quad*8];
      bf16x8 bl = *(const bf16x8*)&l1l[brow * HC + kk + quad*8];
#pragma unroll
      for (int mt = 0; mt < 4; mt++) {
        bf16x8 ah = *(const bf16x8*)&ldsF[(mt*16 + l16)*40 + quad*8];
        bf16x8 al = *(const bf16x8*)&ldsF[2560 + (mt*16 + l16)*40 + quad*8];
        hacc[mt][nt] = __builtin_amdgcn_mfma_f32_16x16x32_bf16(ah, bh, hacc[mt][nt], 0, 0, 0);
        hacc[mt][nt] = __builtin_amdgcn_mfma_f32_16x16x32_bf16(ah, bl, hacc[mt][nt], 0, 0, 0);
        hacc[mt][nt] = __builtin_amdgcn_mfma_f32_16x16x32_bf16(al, bh, hacc[mt][nt], 0, 0, 0);
      }
    }
    __syncthreads();
  }

  f4v wacc[4][4];
#pragma unroll
  for (int mt = 0; mt < 4; mt++)
#pragma unroll
    for (int nt = 0; nt < 4; nt++) wacc[mt][nt] = zf;

  for (int p = 0; p < 4; p++) {
    f4v tacc[4];
#pragma unroll
    for (int mt = 0; mt < 4; mt++) tacc[mt] = zf;
    const size_t b1row = (size_t)(p*64 + wave*16 + l16);
#pragma unroll
    for (int kk = 0; kk < 128; kk += 32) {
      bf16x8 bh = *(const bf16x8*)&fw1h[b1row * HC + kk + quad*8];
      bf16x8 bl = *(const bf16x8*)&fw1l[b1row * HC + kk + quad*8];
#pragma unroll
      for (int mt = 0; mt < 4; mt++) {
        bf16x8 ah = *(const bf16x8*)&ldsA[0][mt*16 + l16][kk + quad*8];
        bf16x8 al = *(const bf16x8*)&ldsA[1][mt*16 + l16][kk + quad*8];
        tacc[mt] = __builtin_amdgcn_mfma_f32_16x16x32_bf16(ah, bh, tacc[mt], 0, 0, 0);
        tacc[mt] = __builtin_amdgcn_mfma_f32_16x16x32_bf16(ah, bl, tacc[mt], 0, 0, 0);
        tacc[mt] = __builtin_amdgcn_mfma_f32_16x16x32_bf16(al, bh, tacc[mt], 0, 0, 0);
      }
    }
    {
      const int col = wave*16 + l16;
      const float bz = fb1[p*64 + col];
#pragma unroll
      for (int mt = 0; mt < 4; mt++) {
        const int rowb = mt*16 + quad*4;
#pragma unroll
        for (int rr = 0; rr < 4; rr++) {
          float v = ssp_f(tacc[mt][rr] + bz);
          unsigned short hb = f2bf(v);
          ldsT[0][rowb+rr][col] = hb;
          ldsT[1][rowb+rr][col] = f2bf(v - bf2f(hb));
        }
      }
    }
    __syncthreads();

#pragma unroll
    for (int kc = 0; kc < 2; kc++) {
      bf16x8 a_h[4], a_l[4];
#pragma unroll
      for (int mt = 0; mt < 4; mt++) {
        a_h[mt] = *(const bf16x8*)&ldsT[0][mt*16 + l16][kc*32 + quad*8];
        a_l[mt] = *(const bf16x8*)&ldsT[1][mt*16 + l16][kc*32 + quad*8];
      }
#pragma unroll
      for (int nt = 0; nt < 4; nt++) {
        const size_t brow = (size_t)(wave*64 + nt*16 + l16);
        bf16x8 bh = *(const bf16x8*)&fw2h[brow * NFC + p*64 + kc*32 + quad*8];
        bf16x8 bl = *(const bf16x8*)&fw2l[brow * NFC + p*64 + kc*32 + quad*8];
#pragma unroll
        for (int mt = 0; mt < 4; mt++) {
          wacc[mt][nt] = __builtin_amdgcn_mfma_f32_16x16x32_bf16(a_h[mt], bh, wacc[mt][nt], 0, 0, 0);
          wacc[mt][nt] = __builtin_amdgcn_mfma_f32_16x16x32_bf16(a_h[mt], bl, wacc[mt][nt], 0, 0, 0);
          wacc[mt][nt] = __builtin_amdgcn_mfma_f32_16x16x32_bf16(a_l[mt], bh, wacc[mt][nt], 0, 0, 0);
        }
      }
    }
    __syncthreads();
  }

#pragma unroll
  for (int nt = 0; nt < 4; nt++) {
    const int col = wave*64 + nt*16 + l16;
    const float bz = fb2[col];
    float accum = 0.f;
    int prev = -1;
#pragma unroll
    for (int mt = 0; mt < 4; mt++) {
#pragma unroll
      for (int rr = 0; rr < 4; rr++) {
        const int prow = mt*16 + quad*4 + rr;
        const int d = sD[prow];
        const float v = (wacc[mt][nt][rr] + bz) * hacc[mt][nt][rr];
        if (d != prev) {
          if (prev >= 0) atomicAdd(&agg[(size_t)prev * NFC + col], accum);
          accum = v; prev = d;
        } else {
          accum += v;
        }
      }
    }
    atomicAdd(&agg[(size_t)prev * NFC + col], accum);
  }
}

// ---------------------------------------------------------------------------
__global__ void pool_kernel(const int* __restrict__ batch, const float* __restrict__ h,
                            float* __restrict__ ssum, float* __restrict__ cnt) {
  int idx = blockIdx.x * blockDim.x + threadIdx.x;
  if (idx >= N_NODES * HC) return;
  int n = idx >> 7, c = idx & 127;
  int b = batch[n];
  atomicAdd(&ssum[(size_t)b*HC + c], h[idx]);
  if (c == 0) atomicAdd(&cnt[b], 1.0f);
}

__global__ __launch_bounds__(256) void head_kernel(
    const float* __restrict__ ssum, const float* __restrict__ cnt,
    const float* __restrict__ w1, const float* __restrict__ b1,
    const float* __restrict__ w2, const float* __restrict__ b2,
    float* __restrict__ y) {
  int g = blockIdx.x;
  __shared__ float gs[HC];
  __shared__ float red[256];
  int tid = threadIdx.x;
  float inv = 1.0f / fmaxf(cnt[g], 1.0f);
  if (tid < HC) gs[tid] = ssum[(size_t)g*HC + tid] * inv;
  __syncthreads();
  float partial = 0.0f;
  for (int f = tid; f < NFFC; f += 256) {
    float acc = b1[f];
    const float* wr = w1 + (size_t)f*HC;
#pragma unroll 8
    for (int k = 0; k < HC; k++) acc = fmaf(gs[k], wr[k], acc);
    float t = 0.5f * acc * (1.0f + erff(acc * 0.70710678118654752440f));
    partial = fmaf(t, w2[f], partial);
  }
  red[tid] = partial;
  __syncthreads();
  for (int s = 128; s > 0; s >>= 1) {
    if (tid < s) red[tid] += red[tid + s];
    __syncthreads();
  }
  if (tid == 0) y[g] = red[0] + b2[0];
}

// ---------------------------------------------------------------------------
extern "C" void kernel_launch(void* const* d_in, const int* in_sizes, int n_in,
                              void* d_out, int out_size, void* d_ws, size_t ws_size,
                              hipStream_t stream) {
  const int*   x     = (const int*)  d_in[0];
  const int*   ei    = (const int*)  d_in[1];
  const float* eattr = (const float*)d_in[2];
  const int*   batch = (const int*)  d_in[3];
  const float* pos   = (const float*)d_in[4];
  const float* vert  = (const float*)d_in[5];
  const float* posw  = (const float*)d_in[6];
  const float* edgew = (const float*)d_in[7];
  const float* fw1   = (const float*)d_in[8];
  const float* fb1   = (const float*)d_in[9];
  const float* fw2   = (const float*)d_in[10];
  const float* fb2   = (const float*)d_in[11];
  const float* l1w   = (const float*)d_in[12];
  const float* l2w   = (const float*)d_in[13];
  const float* l2b   = (const float*)d_in[14];
  const float* l3w   = (const float*)d_in[15];
  const float* l3b   = (const float*)d_in[16];
  const float* emw   = (const float*)d_in[17];
  const float* emb   = (const float*)d_in[18];
  const float* hw1   = (const float*)d_in[19];
  const float* hb1   = (const float*)d_in[20];
  const float* hw2   = (const float*)d_in[21];
  const float* hb2   = (const float*)d_in[22];
  float* out = (float*)d_out;

  char* ws = (char*)d_ws;
  size_t off = 0;
  auto alloc = [&](size_t bytes) { char* p = ws + off; off += (bytes + 511) & ~(size_t)511; return p; };
  float* ea   = (float*)alloc((size_t)N_EDGES*HC*4);
  float* h    = (float*)alloc((size_t)N_NODES*HC*4);
  float* agg  = (float*)alloc((size_t)N_NODES*NFC*4);
  float* ssum = (float*)alloc((size_t)N_GRAPH*HC*4);
  float* cnt  = (float*)alloc((size_t)N_GRAPH*4);
  int* deg    = (int*)alloc((size_t)(N_NODES+1)*4);
  int* cursor = (int*)alloc((size_t)(N_NODES+1)*4);
  int* perm   = (int*)alloc((size_t)N_EDGES*4);
  const int n_fw1 = NLAYER*NFC*HC, n_fw2 = NLAYER*NFC*NFC, n_l1 = NLAYER*NFC*HC;
  const int n_l2 = NLAYER*HC*NFC, n_l3 = NLAYER*HC*HC, n_em = NLAYER*HC*2*HC;
  unsigned short* fw1h = (unsigned short*)alloc((size_t)n_fw1*2);
  unsigned short* fw1l = (unsigned short*)alloc((size_t)n_fw1*2);
  unsigned short* fw2h = (unsigned short*)alloc((size_t)n_fw2*2);
  unsigned short* fw2l = (unsigned short*)alloc((size_t)n_fw2*2);
  unsigned short* l1h  = (unsigned short*)alloc((size_t)n_l1*2);
  unsigned short* l1l  = (unsigned short*)alloc((size_t)n_l1*2);
  unsigned short* l2h  = (unsigned short*)alloc((size_t)n_l2*2);
  unsigned short* l2l  = (unsigned short*)alloc((size_t)n_l2*2);
  unsigned short* l3h  = (unsigned short*)alloc((size_t)n_l3*2);
  unsigned short* l3l  = (unsigned short*)alloc((size_t)n_l3*2);
  unsigned short* emh  = (unsigned short*)alloc((size_t)n_em*2);
  unsigned short* eml  = (unsigned short*)alloc((size_t)n_em*2);

  zeroi_kernel<<<(N_NODES+1+255)/256, 256, 0, stream>>>(deg, N_NODES+1);
  hist_kernel<<<(N_EDGES+255)/256, 256, 0, stream>>>(ei, deg);
  scan_kernel<<<1, 1024, 0, stream>>>(deg, cursor, N_NODES+1);
  perm_kernel<<<(N_EDGES+255)/256, 256, 0, stream>>>(ei, cursor, perm);

  wsplit_kernel<<<(n_fw1+255)/256, 256, 0, stream>>>(fw1, fw1h, fw1l, n_fw1);
  wsplit_kernel<<<(n_fw2+255)/256, 256, 0, stream>>>(fw2, fw2h, fw2l, n_fw2);
  wsplit_kernel<<<(n_l1 +255)/256, 256, 0, stream>>>(l1w, l1h, l1l, n_l1);
  wsplit_kernel<<<(n_l2 +255)/256, 256, 0, stream>>>(l2w, l2h, l2l, n_l2);
  wsplit_kernel<<<(n_l3 +255)/256, 256, 0, stream>>>(l3w, l3h, l3l, n_l3);
  wsplit_kernel<<<(n_em +255)/256, 256, 0, stream>>>(emw, emh, eml, n_em);

  const int GN   = (N_NODES + 127) / 128;   // 391
  const int GE   = (N_EDGES + 127) / 128;   // 1563
  const int GE64 = N_EDGES / 64;            // 3125 (exact)

  embed_kernel<<<N_NODES, 128, 0, stream>>>(x, pos, vert, posw, h);
  edgeproj_kernel<<<(N_EDGES*HC + 255)/256, 256, 0, stream>>>(eattr, edgew, ea);

  for (int i = 0; i < NLAYER; ++i) {
    zero_kernel<<<((N_NODES*NFC/4) + 255)/256, 256, 0, stream>>>(
        (float4*)agg, N_NODES*NFC/4);
    // fused lin1 + filter MLP + scatter
    ffs_kernel<<<GE64, 256, 0, stream>>>(
        ea, l1h + (size_t)i*NFC*HC, l1l + (size_t)i*NFC*HC,
        fw1h + (size_t)i*NFC*HC, fw1l + (size_t)i*NFC*HC, fb1 + (size_t)i*NFC,
        fw2h + (size_t)i*NFC*NFC, fw2l + (size_t)i*NFC*NFC, fb2 + (size_t)i*NFC,
        ei, perm, h, agg);
    // fused l2+l3 node update
    nodeup_kernel<<<GN, 256, 0, stream>>>(
        agg, l2h + (size_t)i*HC*NFC, l2l + (size_t)i*HC*NFC, l2b + (size_t)i*HC,
        l3h + (size_t)i*HC*HC, l3l + (size_t)i*HC*HC, l3b + (size_t)i*HC, h);
    // edge MLP update (gather fused)
    mgemm<EPI_TANH_RES,1><<<dim3(GE,1), 256, 0, stream>>>(
        ea, emh + (size_t)i*HC*2*HC, eml + (size_t)i*HC*2*HC, emb + (size_t)i*HC,
        ea, ea, N_EDGES, 2*HC, HC, ei, h);
  }

  zero_kernel<<<((N_GRAPH*HC/4) + 255)/256, 256, 0, stream>>>((float4*)ssum, N_GRAPH*HC/4);
  zero_kernel<<<((N_GRAPH/4) + 255)/256, 256, 0, stream>>>((float4*)cnt, N_GRAPH/4);
  pool_kernel<<<(N_NODES*HC + 255)/256, 256, 0, stream>>>(batch, h, ssum, cnt);
  head_kernel<<<N_GRAPH, 256, 0, stream>>>(ssum, cnt, hw1, hb1, hw2, hb2, out);
}

// Round 12
// 2577.614 us; speedup vs baseline: 1.6807x; 1.0315x over previous
//
#include <hip/hip_runtime.h>
#include <hip/hip_bf16.h>
#include <math.h>

#define N_NODES 50000
#define N_EDGES 200000
#define N_GRAPH 1024
#define HC      128
#define NFC     256
#define NLAYER  5
#define NFFC    512

enum { EPI_NONE=0, EPI_SSP=2, EPI_RELU_RES=3, EPI_TANH_RES=4 };

typedef short bf16x8 __attribute__((ext_vector_type(8)));
typedef float f4v    __attribute__((ext_vector_type(4)));

// fast ssp: softplus(x)-ln2 via v_exp/v_log (~1e-7 abs err)
__device__ __forceinline__ float ssp_f(float x) {
  float e = __expf(-fabsf(x));
  return fmaxf(x, 0.0f) + __logf(1.0f + e) - 0.69314718055994530942f;
}
// fast tanh via v_exp + v_rcp (~1e-6 err); overflow-safe
__device__ __forceinline__ float tanh_f(float x) {
  float e = __expf(2.0f * fabsf(x));
  float t = 1.0f - 2.0f * __builtin_amdgcn_rcpf(e + 1.0f);
  return copysignf(t, x);
}
__device__ __forceinline__ unsigned short f2bf(float x) {
  union { float f; unsigned u; } v; v.f = x;
  unsigned r = v.u + 0x7fff + ((v.u >> 16) & 1);
  return (unsigned short)(r >> 16);
}
__device__ __forceinline__ float bf2f(unsigned short b) {
  union { unsigned u; float f; } v; v.u = (unsigned)b << 16; return v.f;
}

// ---------------------------------------------------------------------------
__global__ void zero_kernel(float4* __restrict__ p, int n4) {
  int i = blockIdx.x * blockDim.x + threadIdx.x;
  if (i < n4) p[i] = make_float4(0.f, 0.f, 0.f, 0.f);
}
__global__ void zeroi_kernel(int* __restrict__ p, int n) {
  int i = blockIdx.x * blockDim.x + threadIdx.x;
  if (i < n) p[i] = 0;
}

// ---- dst-sort infrastructure ----------------------------------------------
__global__ void hist_kernel(const int* __restrict__ ei, int* __restrict__ deg) {
  int e = blockIdx.x * blockDim.x + threadIdx.x;
  if (e < N_EDGES) atomicAdd(&deg[ei[N_EDGES + e]], 1);
}
__global__ __launch_bounds__(1024) void scan_kernel(
    const int* __restrict__ deg, int* __restrict__ cursor, int n) {
  __shared__ int buf[1024];
  __shared__ int carry;
  if (threadIdx.x == 0) carry = 0;
  __syncthreads();
  for (int base = 0; base < n; base += 1024) {
    int i = base + threadIdx.x;
    int v = (i < n) ? deg[i] : 0;
    buf[threadIdx.x] = v;
    __syncthreads();
    for (int s = 1; s < 1024; s <<= 1) {
      int t = (threadIdx.x >= s) ? buf[threadIdx.x - s] : 0;
      __syncthreads();
      buf[threadIdx.x] += t;
      __syncthreads();
    }
    int excl = carry + buf[threadIdx.x] - v;
    if (i < n) cursor[i] = excl;
    int tot = buf[1023];
    __syncthreads();
    if (threadIdx.x == 0) carry += tot;
    __syncthreads();
  }
}
__global__ void perm_kernel(const int* __restrict__ ei, int* __restrict__ cursor,
                            int* __restrict__ perm) {
  int e = blockIdx.x * blockDim.x + threadIdx.x;
  if (e < N_EDGES) {
    int d = ei[N_EDGES + e];
    int p = atomicAdd(&cursor[d], 1);
    perm[p] = e;
  }
}

// split fp32 weights -> bf16 hi + lo
__global__ void wsplit_kernel(const float* __restrict__ w,
                              unsigned short* __restrict__ hi,
                              unsigned short* __restrict__ lo, int n) {
  int i = blockIdx.x * blockDim.x + threadIdx.x;
  if (i < n) {
    float v = w[i];
    unsigned short hb = f2bf(v);
    hi[i] = hb;
    lo[i] = f2bf(v - bf2f(hb));
  }
}

__global__ void embed_kernel(const int* __restrict__ x, const float* __restrict__ pos,
                             const float* __restrict__ vert, const float* __restrict__ posw,
                             float* __restrict__ h) {
  int n = blockIdx.x;
  int c = threadIdx.x;            // 128 threads
  float v;
  if (c < 80) {
    v = vert[(size_t)x[n] * 80 + c];
  } else {
    int j = c - 80;
    v = pos[n*3+0]*posw[j*3+0] + pos[n*3+1]*posw[j*3+1] + pos[n*3+2]*posw[j*3+2];
  }
  h[(size_t)n*HC + c] = v;
}

__global__ void edgeproj_kernel(const float* __restrict__ eattr, const float* __restrict__ ew,
                                float* __restrict__ ea) {
  int idx = blockIdx.x * blockDim.x + threadIdx.x;
  if (idx >= N_EDGES * HC) return;
  int e = idx >> 7, c = idx & 127;
  const float* a = eattr + (size_t)e*4;
  const float* w = ew + (size_t)c*4;
  ea[idx] = a[0]*w[0] + a[1]*w[1] + a[2]*w[2] + a[3]*w[3];
}

// ---------------------------------------------------------------------------
// Split-bf16 MFMA GEMM (edge-MLP only): C=epi(A@B^T+bias)(+resid).
// GATHER=1: A = cat(A0, h[src]+h[dst]), K=256.
template<int EPI, int GATHER>
__global__ __launch_bounds__(256, 2) void mgemm(
    const float* A0,
    const unsigned short* __restrict__ Bh, const unsigned short* __restrict__ Bl,
    const float* __restrict__ bias, const float* resid, float* C,
    int M, int K, int N, const int* __restrict__ ei, const float* __restrict__ hgat)
{
  __shared__ unsigned short lds[2 * 128 * 40];   // A hi/lo, pitch 40
  __shared__ int sS[128], sD[128];
  const int AH = 0, AL = 5120;

  const int tid  = threadIdx.x;
  const int m0   = blockIdx.x * 128;
  const int n0   = blockIdx.y * 128;
  const int lane = tid & 63, wave = tid >> 6;
  const int quad = lane >> 4, l16 = lane & 15;
  const int wm = (wave >> 1) * 64, wn = (wave & 1) * 64;
  const int r  = tid >> 1;
  const int c0 = (tid & 1) * 16;

  if (GATHER) {
    if (tid < 128) {
      int e  = m0 + tid;
      int ge = (e < M) ? e : (M - 1);
      sS[tid] = ei[ge];
      sD[tid] = ei[N_EDGES + ge];
    }
  }

  f4v acc[4][4];
  const f4v zf = {0.f, 0.f, 0.f, 0.f};
#pragma unroll
  for (int i = 0; i < 4; i++)
#pragma unroll
    for (int j = 0; j < 4; j++) acc[i][j] = zf;

  const bool mok = (m0 + r) < M;
  const size_t arow = (size_t)(m0 + r);

  __syncthreads();

  for (int kk = 0; kk < K; kk += 32) {
    float av[16];
    const int kg = kk + c0;
    if (!GATHER) {
      if (mok) {
        const float* ap = A0 + arow * K + kg;
#pragma unroll
        for (int q = 0; q < 4; q++) *(float4*)&av[q*4] = *(const float4*)(ap + q*4);
      } else {
#pragma unroll
        for (int j = 0; j < 16; j++) av[j] = 0.f;
      }
    } else {
      if (mok) {
        if (kg < HC) {
          const float* ap = A0 + arow * HC + kg;
#pragma unroll
          for (int q = 0; q < 4; q++) *(float4*)&av[q*4] = *(const float4*)(ap + q*4);
        } else {
          const float* p1 = hgat + (size_t)sS[r] * HC + (kg - HC);
          const float* p2 = hgat + (size_t)sD[r] * HC + (kg - HC);
#pragma unroll
          for (int q = 0; q < 4; q++) {
            float4 xa = *(const float4*)(p1 + q*4);
            float4 xb = *(const float4*)(p2 + q*4);
            av[q*4+0] = xa.x + xb.x; av[q*4+1] = xa.y + xb.y;
            av[q*4+2] = xa.z + xb.z; av[q*4+3] = xa.w + xb.w;
          }
        }
      } else {
#pragma unroll
        for (int j = 0; j < 16; j++) av[j] = 0.f;
      }
    }

    bf16x8 bh[4], bl[4];
#pragma unroll
    for (int nt = 0; nt < 4; nt++) {
      const size_t brow = (size_t)(n0 + wn + nt*16 + l16);
      bh[nt] = *(const bf16x8*)&Bh[brow * K + kk + quad*8];
      bl[nt] = *(const bf16x8*)&Bl[brow * K + kk + quad*8];
    }

    __syncthreads();

    unsigned short th[16], tl[16];
#pragma unroll
    for (int j = 0; j < 16; j++) {
      unsigned short hb = f2bf(av[j]);
      th[j] = hb; tl[j] = f2bf(av[j] - bf2f(hb));
    }
    *(bf16x8*)&lds[AH + r*40 + c0]     = *(bf16x8*)&th[0];
    *(bf16x8*)&lds[AH + r*40 + c0 + 8] = *(bf16x8*)&th[8];
    *(bf16x8*)&lds[AL + r*40 + c0]     = *(bf16x8*)&tl[0];
    *(bf16x8*)&lds[AL + r*40 + c0 + 8] = *(bf16x8*)&tl[8];

    __syncthreads();

    bf16x8 ah[4], al[4];
#pragma unroll
    for (int t = 0; t < 4; t++) {
      const int ra = (wm + t*16 + l16) * 40 + quad * 8;
      ah[t] = *(const bf16x8*)&lds[AH + ra];
      al[t] = *(const bf16x8*)&lds[AL + ra];
    }
#pragma unroll
    for (int mt = 0; mt < 4; mt++)
#pragma unroll
      for (int nt = 0; nt < 4; nt++) {
        acc[mt][nt] = __builtin_amdgcn_mfma_f32_16x16x32_bf16(ah[mt], bh[nt], acc[mt][nt], 0, 0, 0);
        acc[mt][nt] = __builtin_amdgcn_mfma_f32_16x16x32_bf16(ah[mt], bl[nt], acc[mt][nt], 0, 0, 0);
        acc[mt][nt] = __builtin_amdgcn_mfma_f32_16x16x32_bf16(al[mt], bh[nt], acc[mt][nt], 0, 0, 0);
      }
  }

#pragma unroll
  for (int nt = 0; nt < 4; nt++) {
    const int ncol = n0 + wn + nt*16 + l16;
    float bz = 0.f;
    if constexpr (EPI != EPI_NONE) bz = bias[ncol];
#pragma unroll
    for (int mt = 0; mt < 4; mt++) {
      const int mb = wm + mt*16 + quad*4;
#pragma unroll
      for (int rr = 0; rr < 4; rr++) {
        const int m = m0 + mb + rr;
        if (m >= M) continue;
        float v = acc[mt][nt][rr] + bz;
        if constexpr (EPI == EPI_SSP)           v = ssp_f(v);
        else if constexpr (EPI == EPI_RELU_RES) v = fmaxf(v, 0.f);
        else if constexpr (EPI == EPI_TANH_RES) v = tanh_f(v);
        if constexpr (EPI == EPI_RELU_RES || EPI == EPI_TANH_RES)
          v += resid[(size_t)m * N + ncol];
        C[(size_t)m * N + ncol] = v;
      }
    }
  }
}

// ---------------------------------------------------------------------------
// Fused node update: h = relu(ssp(agg @ l2^T + b2) @ l3^T + b3) + h.
// t2 lives only in LDS. 128-node tile, 256 threads.
__global__ __launch_bounds__(256, 2) void nodeup_kernel(
    const float* __restrict__ agg,
    const unsigned short* __restrict__ L2h, const unsigned short* __restrict__ L2l,
    const float* __restrict__ b2,
    const unsigned short* __restrict__ L3h, const unsigned short* __restrict__ L3l,
    const float* __restrict__ b3,
    float* h)
{
  __shared__ unsigned short lds[2 * 128 * 136];
  const int AH = 0, AL = 5120;            // A chunk staging (pitch 40)
  const int TH = 0, TL = 17408;           // t2 full tile (pitch 136)

  const int tid  = threadIdx.x;
  const int m0   = blockIdx.x * 128;
  const int lane = tid & 63, wave = tid >> 6;
  const int quad = lane >> 4, l16 = lane & 15;
  const int wm = (wave >> 1) * 64, wn = (wave & 1) * 64;
  const int r  = tid >> 1;
  const int c0 = (tid & 1) * 16;

  const f4v zf = {0.f, 0.f, 0.f, 0.f};
  f4v acc[4][4];
#pragma unroll
  for (int i = 0; i < 4; i++)
#pragma unroll
    for (int j = 0; j < 4; j++) acc[i][j] = zf;

  const bool mok = (m0 + r) < N_NODES;
  const size_t arow = (size_t)(m0 + r);

  for (int kk = 0; kk < NFC; kk += 32) {
    float av[16];
    if (mok) {
      const float* ap = agg + arow * NFC + kk + c0;
#pragma unroll
      for (int q = 0; q < 4; q++) *(float4*)&av[q*4] = *(const float4*)(ap + q*4);
    } else {
#pragma unroll
      for (int j = 0; j < 16; j++) av[j] = 0.f;
    }
    bf16x8 bh[4], bl[4];
#pragma unroll
    for (int nt = 0; nt < 4; nt++) {
      const size_t brow = (size_t)(wn + nt*16 + l16);
      bh[nt] = *(const bf16x8*)&L2h[brow * NFC + kk + quad*8];
      bl[nt] = *(const bf16x8*)&L2l[brow * NFC + kk + quad*8];
    }
    __syncthreads();
    unsigned short th[16], tl[16];
#pragma unroll
    for (int j = 0; j < 16; j++) {
      unsigned short hb = f2bf(av[j]);
      th[j] = hb; tl[j] = f2bf(av[j] - bf2f(hb));
    }
    *(bf16x8*)&lds[AH + r*40 + c0]     = *(bf16x8*)&th[0];
    *(bf16x8*)&lds[AH + r*40 + c0 + 8] = *(bf16x8*)&th[8];
    *(bf16x8*)&lds[AL + r*40 + c0]     = *(bf16x8*)&tl[0];
    *(bf16x8*)&lds[AL + r*40 + c0 + 8] = *(bf16x8*)&tl[8];
    __syncthreads();
    bf16x8 ah[4], al[4];
#pragma unroll
    for (int t = 0; t < 4; t++) {
      const int ra = (wm + t*16 + l16) * 40 + quad * 8;
      ah[t] = *(const bf16x8*)&lds[AH + ra];
      al[t] = *(const bf16x8*)&lds[AL + ra];
    }
#pragma unroll
    for (int mt = 0; mt < 4; mt++)
#pragma unroll
      for (int nt = 0; nt < 4; nt++) {
        acc[mt][nt] = __builtin_amdgcn_mfma_f32_16x16x32_bf16(ah[mt], bh[nt], acc[mt][nt], 0, 0, 0);
        acc[mt][nt] = __builtin_amdgcn_mfma_f32_16x16x32_bf16(ah[mt], bl[nt], acc[mt][nt], 0, 0, 0);
        acc[mt][nt] = __builtin_amdgcn_mfma_f32_16x16x32_bf16(al[mt], bh[nt], acc[mt][nt], 0, 0, 0);
      }
  }
  __syncthreads();

#pragma unroll
  for (int nt = 0; nt < 4; nt++) {
    const int col = wn + nt*16 + l16;
    const float bz = b2[col];
#pragma unroll
    for (int mt = 0; mt < 4; mt++) {
      const int rowb = wm + mt*16 + quad*4;
#pragma unroll
      for (int rr = 0; rr < 4; rr++) {
        float v = ssp_f(acc[mt][nt][rr] + bz);
        unsigned short hb = f2bf(v);
        lds[TH + (rowb+rr)*136 + col] = hb;
        lds[TL + (rowb+rr)*136 + col] = f2bf(v - bf2f(hb));
      }
    }
  }
  __syncthreads();

  f4v acc2[4][4];
#pragma unroll
  for (int i = 0; i < 4; i++)
#pragma unroll
    for (int j = 0; j < 4; j++) acc2[i][j] = zf;

  for (int kk = 0; kk < HC; kk += 32) {
    bf16x8 bh[4], bl[4];
#pragma unroll
    for (int nt = 0; nt < 4; nt++) {
      const size_t brow = (size_t)(wn + nt*16 + l16);
      bh[nt] = *(const bf16x8*)&L3h[brow * HC + kk + quad*8];
      bl[nt] = *(const bf16x8*)&L3l[brow * HC + kk + quad*8];
    }
    bf16x8 ah[4], al[4];
#pragma unroll
    for (int t = 0; t < 4; t++) {
      const int ra = (wm + t*16 + l16) * 136 + kk + quad * 8;
      ah[t] = *(const bf16x8*)&lds[TH + ra];
      al[t] = *(const bf16x8*)&lds[TL + ra];
    }
#pragma unroll
    for (int mt = 0; mt < 4; mt++)
#pragma unroll
      for (int nt = 0; nt < 4; nt++) {
        acc2[mt][nt] = __builtin_amdgcn_mfma_f32_16x16x32_bf16(ah[mt], bh[nt], acc2[mt][nt], 0, 0, 0);
        acc2[mt][nt] = __builtin_amdgcn_mfma_f32_16x16x32_bf16(ah[mt], bl[nt], acc2[mt][nt], 0, 0, 0);
        acc2[mt][nt] = __builtin_amdgcn_mfma_f32_16x16x32_bf16(al[mt], bh[nt], acc2[mt][nt], 0, 0, 0);
      }
  }

#pragma unroll
  for (int nt = 0; nt < 4; nt++) {
    const int ncol = wn + nt*16 + l16;
    const float bz = b3[ncol];
#pragma unroll
    for (int mt = 0; mt < 4; mt++) {
      const int mb = wm + mt*16 + quad*4;
#pragma unroll
      for (int rr = 0; rr < 4; rr++) {
        const int m = m0 + mb + rr;
        if (m < N_NODES) {
          const size_t idx = (size_t)m * HC + ncol;
          h[idx] = fmaxf(acc2[mt][nt][rr] + bz, 0.f) + h[idx];
        }
      }
    }
  }
}

// ---------------------------------------------------------------------------
// Fused lin1 + filter MLP + in-register run-reduced scatter, dst-sorted edges.
// R12: de-barriered staging — ea loaded to regs at block start (held split),
// full h-tile staged once into ldsA, barrier-free hacc GEMM, then ldsA
// overwritten with the held ea. 12 barriers vs 17.
__device__ __forceinline__ int sigma_row(int r) {
  return ((r >> 2) & 3) * 16 + (r >> 4) * 4 + (r & 3);
}
__global__ __launch_bounds__(256, 3) void ffs_kernel(
    const float* __restrict__ ea,
    const unsigned short* __restrict__ l1h, const unsigned short* __restrict__ l1l,
    const unsigned short* __restrict__ fw1h, const unsigned short* __restrict__ fw1l,
    const float* __restrict__ fb1,
    const unsigned short* __restrict__ fw2h, const unsigned short* __restrict__ fw2l,
    const float* __restrict__ fb2, const int* __restrict__ ei,
    const int* __restrict__ perm,
    const float* __restrict__ hfeat, float* agg)
{
  __shared__ unsigned short ldsA[2][64][136];   // h-tile then ea-tile (split)
  __shared__ unsigned short ldsT[2][64][72];    // T phase chunk
  __shared__ int sS[64], sD[64];

  const int tid  = threadIdx.x;
  const int m0   = blockIdx.x * 64;
  const int lane = tid & 63, wave = tid >> 6;
  const int quad = lane >> 4, l16 = lane & 15;
  const int r = tid >> 2, cb = (tid & 3) * 32;

  // ---- issue ea loads immediately (overlap with everything below) ----
  const int pe = perm[m0 + sigma_row(r)];
  float eav[32];
  {
    const float* ap = ea + (size_t)pe * HC + cb;
#pragma unroll
    for (int q = 0; q < 8; q++) *(float4*)&eav[q*4] = *(const float4*)(ap + q*4);
  }
  if (tid < 64) {
    int pe2 = perm[m0 + sigma_row(tid)];
    sS[tid] = ei[pe2];
    sD[tid] = ei[N_EDGES + pe2];
  }
  // convert ea to split regs (held until after hacc)
  unsigned short eth[32], etl[32];
#pragma unroll
  for (int j = 0; j < 32; j++) {
    unsigned short hb = f2bf(eav[j]);
    eth[j] = hb; etl[j] = f2bf(eav[j] - bf2f(hb));
  }

  __syncthreads();   // sS visible

  // ---- stage full h[src] tile into ldsA (split, pitch 136) ----
  {
    const float* hp_ = hfeat + (size_t)sS[r] * HC + cb;
    float hv[32];
#pragma unroll
    for (int q = 0; q < 8; q++) *(float4*)&hv[q*4] = *(const float4*)(hp_ + q*4);
    unsigned short th[32], tl[32];
#pragma unroll
    for (int j = 0; j < 32; j++) {
      unsigned short hb = f2bf(hv[j]);
      th[j] = hb; tl[j] = f2bf(hv[j] - bf2f(hb));
    }
#pragma unroll
    for (int q = 0; q < 4; q++) {
      *(bf16x8*)&ldsA[0][r][cb + q*8] = *(bf16x8*)&th[q*8];
      *(bf16x8*)&ldsA[1][r][cb + q*8] = *(bf16x8*)&tl[q*8];
    }
  }

  const f4v zf = {0.f, 0.f, 0.f, 0.f};
  f4v hacc[4][4];
#pragma unroll
  for (int mt = 0; mt < 4; mt++)
#pragma unroll
    for (int nt = 0; nt < 4; nt++) hacc[mt][nt] = zf;

  __syncthreads();   // h staged

  // ---- hacc = h @ l1^T (barrier-free: ldsA stable, B wave-distinct) ----
  for (int kk = 0; kk < 128; kk += 32) {
#pragma unroll
    for (int nt = 0; nt < 4; nt++) {
      const size_t brow = (size_t)(wave*64 + nt*16 + l16);
      bf16x8 bh = *(const bf16x8*)&l1h[brow * HC + kk + quad*8];
      bf16x8 bl = *(const bf16x8*)&l1l[brow * HC + kk + quad*8];
#pragma unroll
      for (int mt = 0; mt < 4; mt++) {
        bf16x8 ah = *(const bf16x8*)&ldsA[0][mt*16 + l16][kk + quad*8];
        bf16x8 al = *(const bf16x8*)&ldsA[1][mt*16 + l16][kk + quad*8];
        hacc[mt][nt] = __builtin_amdgcn_mfma_f32_16x16x32_bf16(ah, bh, hacc[mt][nt], 0, 0, 0);
        hacc[mt][nt] = __builtin_amdgcn_mfma_f32_16x16x32_bf16(ah, bl, hacc[mt][nt], 0, 0, 0);
        hacc[mt][nt] = __builtin_amdgcn_mfma_f32_16x16x32_bf16(al, bh, hacc[mt][nt], 0, 0, 0);
      }
    }
  }
  __syncthreads();   // all ldsA h reads done

  // ---- overwrite ldsA with held ea tile ----
#pragma unroll
  for (int q = 0; q < 4; q++) {
    *(bf16x8*)&ldsA[0][r][cb + q*8] = *(bf16x8*)&eth[q*8];
    *(bf16x8*)&ldsA[1][r][cb + q*8] = *(bf16x8*)&etl[q*8];
  }

  f4v wacc[4][4];
#pragma unroll
  for (int mt = 0; mt < 4; mt++)
#pragma unroll
    for (int nt = 0; nt < 4; nt++) wacc[mt][nt] = zf;

  __syncthreads();   // ea staged

  for (int p = 0; p < 4; p++) {
    // ---- GEMM1: T_p[64,64]; wave owns COLS (fw1 fragments wave-distinct) ----
    f4v tacc[4];
#pragma unroll
    for (int mt = 0; mt < 4; mt++) tacc[mt] = zf;
    const size_t b1row = (size_t)(p*64 + wave*16 + l16);
#pragma unroll
    for (int kk = 0; kk < 128; kk += 32) {
      bf16x8 bh = *(const bf16x8*)&fw1h[b1row * HC + kk + quad*8];
      bf16x8 bl = *(const bf16x8*)&fw1l[b1row * HC + kk + quad*8];
#pragma unroll
      for (int mt = 0; mt < 4; mt++) {
        bf16x8 ah = *(const bf16x8*)&ldsA[0][mt*16 + l16][kk + quad*8];
        bf16x8 al = *(const bf16x8*)&ldsA[1][mt*16 + l16][kk + quad*8];
        tacc[mt] = __builtin_amdgcn_mfma_f32_16x16x32_bf16(ah, bh, tacc[mt], 0, 0, 0);
        tacc[mt] = __builtin_amdgcn_mfma_f32_16x16x32_bf16(ah, bl, tacc[mt], 0, 0, 0);
        tacc[mt] = __builtin_amdgcn_mfma_f32_16x16x32_bf16(al, bh, tacc[mt], 0, 0, 0);
      }
    }
    {
      const int col = wave*16 + l16;
      const float bz = fb1[p*64 + col];
#pragma unroll
      for (int mt = 0; mt < 4; mt++) {
        const int rowb = mt*16 + quad*4;
#pragma unroll
        for (int rr = 0; rr < 4; rr++) {
          float v = ssp_f(tacc[mt][rr] + bz);
          unsigned short hb = f2bf(v);
          ldsT[0][rowb+rr][col] = hb;
          ldsT[1][rowb+rr][col] = f2bf(v - bf2f(hb));
        }
      }
    }
    __syncthreads();

    // ---- GEMM2 partial: W += T_p @ fw2[:, p*64..+64]^T (B wave-distinct) ----
#pragma unroll
    for (int kc = 0; kc < 2; kc++) {
      bf16x8 a_h[4], a_l[4];
#pragma unroll
      for (int mt = 0; mt < 4; mt++) {
        a_h[mt] = *(const bf16x8*)&ldsT[0][mt*16 + l16][kc*32 + quad*8];
        a_l[mt] = *(const bf16x8*)&ldsT[1][mt*16 + l16][kc*32 + quad*8];
      }
#pragma unroll
      for (int nt = 0; nt < 4; nt++) {
        const size_t brow = (size_t)(wave*64 + nt*16 + l16);
        bf16x8 bh = *(const bf16x8*)&fw2h[brow * NFC + p*64 + kc*32 + quad*8];
        bf16x8 bl = *(const bf16x8*)&fw2l[brow * NFC + p*64 + kc*32 + quad*8];
#pragma unroll
        for (int mt = 0; mt < 4; mt++) {
          wacc[mt][nt] = __builtin_amdgcn_mfma_f32_16x16x32_bf16(a_h[mt], bh, wacc[mt][nt], 0, 0, 0);
          wacc[mt][nt] = __builtin_amdgcn_mfma_f32_16x16x32_bf16(a_h[mt], bl, wacc[mt][nt], 0, 0, 0);
          wacc[mt][nt] = __builtin_amdgcn_mfma_f32_16x16x32_bf16(a_l[mt], bh, wacc[mt][nt], 0, 0, 0);
        }
      }
    }
    __syncthreads();
  }

  // ---- in-register run-reduced scatter: v = (W+b2) * hj ----
#pragma unroll
  for (int nt = 0; nt < 4; nt++) {
    const int col = wave*64 + nt*16 + l16;
    const float bz = fb2[col];
    float accum = 0.f;
    int prev = -1;
#pragma unroll
    for (int mt = 0; mt < 4; mt++) {
#pragma unroll
      for (int rr = 0; rr < 4; rr++) {
        const int prow = mt*16 + quad*4 + rr;
        const int d = sD[prow];
        const float v = (wacc[mt][nt][rr] + bz) * hacc[mt][nt][rr];
        if (d != prev) {
          if (prev >= 0) atomicAdd(&agg[(size_t)prev * NFC + col], accum);
          accum = v; prev = d;
        } else {
          accum += v;
        }
      }
    }
    atomicAdd(&agg[(size_t)prev * NFC + col], accum);
  }
}

// ---------------------------------------------------------------------------
__global__ void pool_kernel(const int* __restrict__ batch, const float* __restrict__ h,
                            float* __restrict__ ssum, float* __restrict__ cnt) {
  int idx = blockIdx.x * blockDim.x + threadIdx.x;
  if (idx >= N_NODES * HC) return;
  int n = idx >> 7, c = idx & 127;
  int b = batch[n];
  atomicAdd(&ssum[(size_t)b*HC + c], h[idx]);
  if (c == 0) atomicAdd(&cnt[b], 1.0f);
}

__global__ __launch_bounds__(256) void head_kernel(
    const float* __restrict__ ssum, const float* __restrict__ cnt,
    const float* __restrict__ w1, const float* __restrict__ b1,
    const float* __restrict__ w2, const float* __restrict__ b2,
    float* __restrict__ y) {
  int g = blockIdx.x;
  __shared__ float gs[HC];
  __shared__ float red[256];
  int tid = threadIdx.x;
  float inv = 1.0f / fmaxf(cnt[g], 1.0f);
  if (tid < HC) gs[tid] = ssum[(size_t)g*HC + tid] * inv;
  __syncthreads();
  float partial = 0.0f;
  for (int f = tid; f < NFFC; f += 256) {
    float acc = b1[f];
    const float* wr = w1 + (size_t)f*HC;
#pragma unroll 8
    for (int k = 0; k < HC; k++) acc = fmaf(gs[k], wr[k], acc);
    float t = 0.5f * acc * (1.0f + erff(acc * 0.70710678118654752440f));
    partial = fmaf(t, w2[f], partial);
  }
  red[tid] = partial;
  __syncthreads();
  for (int s = 128; s > 0; s >>= 1) {
    if (tid < s) red[tid] += red[tid + s];
    __syncthreads();
  }
  if (tid == 0) y[g] = red[0] + b2[0];
}

// ---------------------------------------------------------------------------
extern "C" void kernel_launch(void* const* d_in, const int* in_sizes, int n_in,
                              void* d_out, int out_size, void* d_ws, size_t ws_size,
                              hipStream_t stream) {
  const int*   x     = (const int*)  d_in[0];
  const int*   ei    = (const int*)  d_in[1];
  const float* eattr = (const float*)d_in[2];
  const int*   batch = (const int*)  d_in[3];
  const float* pos   = (const float*)d_in[4];
  const float* vert  = (const float*)d_in[5];
  const float* posw  = (const float*)d_in[6];
  const float* edgew = (const float*)d_in[7];
  const float* fw1   = (const float*)d_in[8];
  const float* fb1   = (const float*)d_in[9];
  const float* fw2   = (const float*)d_in[10];
  const float* fb2   = (const float*)d_in[11];
  const float* l1w   = (const float*)d_in[12];
  const float* l2w   = (const float*)d_in[13];
  const float* l2b   = (const float*)d_in[14];
  const float* l3w   = (const float*)d_in[15];
  const float* l3b   = (const float*)d_in[16];
  const float* emw   = (const float*)d_in[17];
  const float* emb   = (const float*)d_in[18];
  const float* hw1   = (const float*)d_in[19];
  const float* hb1   = (const float*)d_in[20];
  const float* hw2   = (const float*)d_in[21];
  const float* hb2   = (const float*)d_in[22];
  float* out = (float*)d_out;

  char* ws = (char*)d_ws;
  size_t off = 0;
  auto alloc = [&](size_t bytes) { char* p = ws + off; off += (bytes + 511) & ~(size_t)511; return p; };
  float* ea   = (float*)alloc((size_t)N_EDGES*HC*4);
  float* h    = (float*)alloc((size_t)N_NODES*HC*4);
  float* agg  = (float*)alloc((size_t)N_NODES*NFC*4);
  float* ssum = (float*)alloc((size_t)N_GRAPH*HC*4);
  float* cnt  = (float*)alloc((size_t)N_GRAPH*4);
  int* deg    = (int*)alloc((size_t)(N_NODES+1)*4);
  int* cursor = (int*)alloc((size_t)(N_NODES+1)*4);
  int* perm   = (int*)alloc((size_t)N_EDGES*4);
  const int n_fw1 = NLAYER*NFC*HC, n_fw2 = NLAYER*NFC*NFC, n_l1 = NLAYER*NFC*HC;
  const int n_l2 = NLAYER*HC*NFC, n_l3 = NLAYER*HC*HC, n_em = NLAYER*HC*2*HC;
  unsigned short* fw1h = (unsigned short*)alloc((size_t)n_fw1*2);
  unsigned short* fw1l = (unsigned short*)alloc((size_t)n_fw1*2);
  unsigned short* fw2h = (unsigned short*)alloc((size_t)n_fw2*2);
  unsigned short* fw2l = (unsigned short*)alloc((size_t)n_fw2*2);
  unsigned short* l1h  = (unsigned short*)alloc((size_t)n_l1*2);
  unsigned short* l1l  = (unsigned short*)alloc((size_t)n_l1*2);
  unsigned short* l2h  = (unsigned short*)alloc((size_t)n_l2*2);
  unsigned short* l2l  = (unsigned short*)alloc((size_t)n_l2*2);
  unsigned short* l3h  = (unsigned short*)alloc((size_t)n_l3*2);
  unsigned short* l3l  = (unsigned short*)alloc((size_t)n_l3*2);
  unsigned short* emh  = (unsigned short*)alloc((size_t)n_em*2);
  unsigned short* eml  = (unsigned short*)alloc((size_t)n_em*2);

  zeroi_kernel<<<(N_NODES+1+255)/256, 256, 0, stream>>>(deg, N_NODES+1);
  hist_kernel<<<(N_EDGES+255)/256, 256, 0, stream>>>(ei, deg);
  scan_kernel<<<1, 1024, 0, stream>>>(deg, cursor, N_NODES+1);
  perm_kernel<<<(N_EDGES+255)/256, 256, 0, stream>>>(ei, cursor, perm);

  wsplit_kernel<<<(n_fw1+255)/256, 256, 0, stream>>>(fw1, fw1h, fw1l, n_fw1);
  wsplit_kernel<<<(n_fw2+255)/256, 256, 0, stream>>>(fw2, fw2h, fw2l, n_fw2);
  wsplit_kernel<<<(n_l1 +255)/256, 256, 0, stream>>>(l1w, l1h, l1l, n_l1);
  wsplit_kernel<<<(n_l2 +255)/256, 256, 0, stream>>>(l2w, l2h, l2l, n_l2);
  wsplit_kernel<<<(n_l3 +255)/256, 256, 0, stream>>>(l3w, l3h, l3l, n_l3);
  wsplit_kernel<<<(n_em +255)/256, 256, 0, stream>>>(emw, emh, eml, n_em);

  const int GN   = (N_NODES + 127) / 128;   // 391
  const int GE   = (N_EDGES + 127) / 128;   // 1563
  const int GE64 = N_EDGES / 64;            // 3125 (exact)

  embed_kernel<<<N_NODES, 128, 0, stream>>>(x, pos, vert, posw, h);
  edgeproj_kernel<<<(N_EDGES*HC + 255)/256, 256, 0, stream>>>(eattr, edgew, ea);

  for (int i = 0; i < NLAYER; ++i) {
    zero_kernel<<<((N_NODES*NFC/4) + 255)/256, 256, 0, stream>>>(
        (float4*)agg, N_NODES*NFC/4);
    ffs_kernel<<<GE64, 256, 0, stream>>>(
        ea, l1h + (size_t)i*NFC*HC, l1l + (size_t)i*NFC*HC,
        fw1h + (size_t)i*NFC*HC, fw1l + (size_t)i*NFC*HC, fb1 + (size_t)i*NFC,
        fw2h + (size_t)i*NFC*NFC, fw2l + (size_t)i*NFC*NFC, fb2 + (size_t)i*NFC,
        ei, perm, h, agg);
    nodeup_kernel<<<GN, 256, 0, stream>>>(
        agg, l2h + (size_t)i*HC*NFC, l2l + (size_t)i*HC*NFC, l2b + (size_t)i*HC,
        l3h + (size_t)i*HC*HC, l3l + (size_t)i*HC*HC, l3b + (size_t)i*HC, h);
    // edge-MLP update is DEAD at the last layer (ea never read again)
    if (i < NLAYER - 1) {
      mgemm<EPI_TANH_RES,1><<<dim3(GE,1), 256, 0, stream>>>(
          ea, emh + (size_t)i*HC*2*HC, eml + (size_t)i*HC*2*HC, emb + (size_t)i*HC,
          ea, ea, N_EDGES, 2*HC, HC, ei, h);
    }
  }

  zero_kernel<<<((N_GRAPH*HC/4) + 255)/256, 256, 0, stream>>>((float4*)ssum, N_GRAPH*HC/4);
  zero_kernel<<<((N_GRAPH/4) + 255)/256, 256, 0, stream>>>((float4*)cnt, N_GRAPH/4);
  pool_kernel<<<(N_NODES*HC + 255)/256, 256, 0, stream>>>(batch, h, ssum, cnt);
  head_kernel<<<N_GRAPH, 256, 0, stream>>>(ssum, cnt, hw1, hb1, hw2, hb2, out);
}